// Round 10
// baseline (494.163 us; speedup 1.0000x reference)
//
#include <hip/hip_runtime.h>
#include <math.h>

#define N_NODES 20000
#define N_EDGES 320000
#define NENT    2000
#define KNN_K   10

typedef __attribute__((ext_vector_type(4))) float f32x4;
typedef __attribute__((ext_vector_type(8))) short bf16x8;
typedef __attribute__((ext_vector_type(8))) unsigned short u16x8;
typedef __attribute__((ext_vector_type(4))) unsigned short u16x4;

__device__ __forceinline__ unsigned short f2bf(float f) {
  union { float f; unsigned u; } v; v.f = f;
  unsigned r = v.u + 0x7fffu + ((v.u >> 16) & 1u);
  return (unsigned short)(r >> 16);
}
__device__ __forceinline__ float bf2f(unsigned short u) {
  union { unsigned u; float f; } v; v.u = ((unsigned)u) << 16;
  return v.f;
}
__device__ __forceinline__ float sigmoidf(float x) {
  return 1.f / (1.f + __expf(-x));
}
// async global->LDS, 16B per lane; lds dest = wave-uniform base + lane*16
__device__ __forceinline__ void gload_lds16(const unsigned short* g, unsigned short* lds) {
  __builtin_amdgcn_global_load_lds(
      (const __attribute__((address_space(1))) unsigned int*)g,
      (__attribute__((address_space(3))) unsigned int*)lds, 16, 0, 0);
}

// ---------------- h0 = concat(position, w_embed) -> bf16 ----------------
__global__ void k_build_h0(const float* __restrict__ pos, const float* __restrict__ wemb,
                           unsigned short* __restrict__ h0) {
  int i = blockIdx.x * blockDim.x + threadIdx.x;
  if (i >= N_NODES * 128) return;
  int n = i >> 7, c = i & 127;
  float v = (c < 2) ? pos[n * 2 + c] : wemb[n * 126 + (c - 2)];
  h0[i] = f2bf(v);
}

// ---------------- generic f32 -> bf16 (n multiple of 4) ----------------
__global__ void k_f2bf(const float* __restrict__ in, unsigned short* __restrict__ out, int n) {
  int i = blockIdx.x * blockDim.x + threadIdx.x;
  if (i * 4 >= n) return;
  f32x4 v = *(const f32x4*)(in + i * 4);
  u16x4 o;
  o[0] = f2bf(v[0]); o[1] = f2bf(v[1]); o[2] = f2bf(v[2]); o[3] = f2bf(v[3]);
  *(u16x4*)(out + i * 4) = o;
}

// ---- ALL weight conversions in one launch ----
__global__ void k_conv_weights(
    const float* __restrict__ W1, const float* __restrict__ Wr1,
    const float* __restrict__ W2, const float* __restrict__ Wr2,
    const float* __restrict__ W3, const float* __restrict__ Wr3,
    const float* __restrict__ Wg1, const float* __restrict__ Wl1,
    unsigned short* __restrict__ wbf1, unsigned short* __restrict__ wbf2,
    unsigned short* __restrict__ wbf3, unsigned short* __restrict__ wg1b,
    unsigned short* __restrict__ wl1b) {
  int i4 = (blockIdx.x * blockDim.x + threadIdx.x) * 4;
  const float* src;
  unsigned short* dst;
  if (i4 < 131072) {
    src = (i4 < 65536) ? (W1 + i4) : (Wr1 + i4 - 65536);
    dst = wbf1 + i4;
  } else if ((i4 -= 131072) < 524288) {
    src = (i4 < 262144) ? (W2 + i4) : (Wr2 + i4 - 262144);
    dst = wbf2 + i4;
  } else if ((i4 -= 524288) < 524288) {
    src = (i4 < 262144) ? (W3 + i4) : (Wr3 + i4 - 262144);
    dst = wbf3 + i4;
  } else if ((i4 -= 524288) < 32768) {
    // swizzled 128x128: 4 consecutive k stay contiguous after swizzle
    const float* W = (i4 < 16384) ? Wg1 : Wl1;
    unsigned short* O = (i4 < 16384) ? wg1b : wl1b;
    int ii = i4 & 16383;
    int row = ii >> 7, k = ii & 127;
    int sg = (k >> 3) ^ (row & 15);
    src = W + ii;
    dst = O + row * 128 + sg * 8 + (k & 7);
  } else {
    return;
  }
  f32x4 v = *(const f32x4*)src;
  u16x4 o;
  o[0] = f2bf(v[0]); o[1] = f2bf(v[1]); o[2] = f2bf(v[2]); o[3] = f2bf(v[3]);
  *(u16x4*)dst = o;
}

// ------- bf16 MFMA GEMM + fused el/er epilogue -------
// C[M,Nc] = A[M,K] * B[Nc,K]^T (bf16 out). For feat col-blocks (bn<512),
// also accumulates el[row,h] += sum_d C_f32(row, h*128+d)*al[h,d] (same for er/ar)
// via one f32 atomicAdd per (row, head, wave-half).
__global__ __launch_bounds__(256) void k_gemm_bt(
    const unsigned short* __restrict__ A, const unsigned short* __restrict__ B,
    unsigned short* __restrict__ C, int M, int Nc, int K,
    const float* __restrict__ al, const float* __restrict__ ar,
    float* __restrict__ el, float* __restrict__ er) {
  __shared__ __align__(16) unsigned short As[128 * 64];
  __shared__ __align__(16) unsigned short Bs[128 * 64];
  const int bm = blockIdx.x * 128, bn = blockIdx.y * 128;
  const int t = threadIdx.x;
  const int l = t & 63, w = t >> 6;
  const int wr = w >> 1, wc = w & 1;
  f32x4 acc[4][4];
#pragma unroll
  for (int m = 0; m < 4; ++m)
#pragma unroll
    for (int n = 0; n < 4; ++n) acc[m][n] = (f32x4){0.f, 0.f, 0.f, 0.f};

  for (int kb = 0; kb < K; kb += 64) {
    __syncthreads();
#pragma unroll
    for (int i = 0; i < 4; ++i) {
      int c = t + 256 * i;         // 1024 16B-chunks per tile
      int row = c >> 3, cc = c & 7;
      int scc = cc ^ (row & 7);    // pre-swizzled SOURCE granule (read side keeps same XOR)
      int ar2 = bm + row; if (ar2 > M - 1) ar2 = M - 1;
      gload_lds16(A + (size_t)ar2 * K + kb + scc * 8, &As[(size_t)(w * 64 + 256 * i) * 8]);
      gload_lds16(B + (size_t)(bn + row) * K + kb + scc * 8,
                  &Bs[(size_t)(w * 64 + 256 * i) * 8]);
    }
    __syncthreads();
#pragma unroll
    for (int kk = 0; kk < 2; ++kk) {
      bf16x8 af[4], bfr[4];
#pragma unroll
      for (int m = 0; m < 4; ++m) {
        int row = wr * 64 + m * 16 + (l & 15);
        int g = (kk * 4 + (l >> 4)) ^ (row & 7);
        af[m] = *(const bf16x8*)&As[row * 64 + g * 8];
      }
#pragma unroll
      for (int n = 0; n < 4; ++n) {
        int row = wc * 64 + n * 16 + (l & 15);
        int g = (kk * 4 + (l >> 4)) ^ (row & 7);
        bfr[n] = *(const bf16x8*)&Bs[row * 64 + g * 8];
      }
#pragma unroll
      for (int m = 0; m < 4; ++m)
#pragma unroll
        for (int n = 0; n < 4; ++n)
          acc[m][n] = __builtin_amdgcn_mfma_f32_16x16x32_bf16(af[m], bfr[n], acc[m][n], 0, 0, 0);
    }
  }
#pragma unroll
  for (int m = 0; m < 4; ++m) {
    int r0 = bm + wr * 64 + m * 16 + ((l >> 4) << 2);
#pragma unroll
    for (int n = 0; n < 4; ++n) {
      int c0 = bn + wc * 64 + n * 16 + (l & 15);
#pragma unroll
      for (int r = 0; r < 4; ++r) {
        int row = r0 + r;
        if (row < M) C[(size_t)row * Nc + c0] = f2bf(acc[m][n][r]);
      }
    }
  }
  // ---- fused el/er (feat col-blocks only) ----
  if (bn < 512) {
    int h = bn >> 7;
    float alv[4], arv[4];
#pragma unroll
    for (int n = 0; n < 4; ++n) {
      int cw = wc * 64 + n * 16 + (l & 15);
      alv[n] = al[h * 128 + cw];
      arv[n] = ar[h * 128 + cw];
    }
#pragma unroll
    for (int m = 0; m < 4; ++m) {
#pragma unroll
      for (int r = 0; r < 4; ++r) {
        float pl = 0.f, pr = 0.f;
#pragma unroll
        for (int n = 0; n < 4; ++n) {
          pl += acc[m][n][r] * alv[n];
          pr += acc[m][n][r] * arv[n];
        }
#pragma unroll
        for (int d = 1; d < 16; d <<= 1) {
          pl += __shfl_xor(pl, d);
          pr += __shfl_xor(pr, d);
        }
        if ((l & 15) == 0) {
          int row = bm + wr * 64 + m * 16 + ((l >> 4) << 2) + r;
          if (row < M) {
            atomicAdd(&el[row * 4 + h], pl);
            atomicAdd(&er[row * 4 + h], pr);
          }
        }
      }
    }
  }
}

// ---------------- CSR build ----------------
__global__ void k_hist(const int* __restrict__ dst, int* __restrict__ indeg) {
  int e = blockIdx.x * blockDim.x + threadIdx.x;
  if (e < N_EDGES) atomicAdd(&indeg[dst[e]], 1);
}

__global__ __launch_bounds__(1024) void k_scan_fast(const int* __restrict__ indeg,
                                                    int* __restrict__ indptr,
                                                    int* __restrict__ cursor) {
  __shared__ int wsum[16];
  const int t = threadIdx.x;
  const int l = t & 63, w = t >> 6;
  const int CH = 20;  // 1024*20 >= 20000
  int base = t * CH;
  int vals[CH];
  int s = 0;
#pragma unroll
  for (int i = 0; i < CH; ++i) {
    int idx = base + i;
    int v = (idx < N_NODES) ? indeg[idx] : 0;
    vals[i] = v;
    s += v;
  }
  int ss = s;
#pragma unroll
  for (int d = 1; d < 64; d <<= 1) { int o = __shfl_up(ss, d); if (l >= d) ss += o; }
  if (l == 63) wsum[w] = ss;
  __syncthreads();
  if (t < 16) {
    int v = wsum[t];
#pragma unroll
    for (int d = 1; d < 16; d <<= 1) { int o = __shfl_up(v, d); if (t >= d) v += o; }
    wsum[t] = v;
  }
  __syncthreads();
  int run = ((w > 0) ? wsum[w - 1] : 0) + ss - s;
  if (t == 0) indptr[0] = 0;
#pragma unroll
  for (int i = 0; i < CH; ++i) {
    int idx = base + i;
    if (idx < N_NODES) {
      cursor[idx] = run;
      run += vals[i];
      indptr[idx + 1] = run;
    }
  }
}

__global__ void k_scatter(const int* __restrict__ src, const int* __restrict__ dst,
                          int* __restrict__ cursor, int* __restrict__ csr_src) {
  int e = blockIdx.x * blockDim.x + threadIdx.x;
  if (e < N_EDGES) {
    int p = atomicAdd(&cursor[dst[e]], 1);
    csr_src[p] = src[e];
  }
}

// ---------------- GAT edge-softmax + aggregation (wave per dst node) ----------------
// no-max softmax (alpha invariant to shift; |e| << 88 so exp is safe),
// 4-deep unrolled gather loop
template <bool FINAL>
__global__ void k_gat_agg(const unsigned short* __restrict__ feat,
                          const unsigned short* __restrict__ hres, int fstride,
                          const float* __restrict__ el, const float* __restrict__ er,
                          const int* __restrict__ indptr, const int* __restrict__ csr_src,
                          unsigned short* __restrict__ hnext, float* __restrict__ h3,
                          unsigned short* __restrict__ h3b) {
  int wid = (blockIdx.x * blockDim.x + threadIdx.x) >> 6;
  if (wid >= N_NODES) return;
  int l = threadIdx.x & 63;
  int g = l >> 4;
  int beg = indptr[wid], end = indptr[wid + 1];
  float er_g = er[wid * 4 + g];
  float asum = 0.f;
  float acc[8];
#pragma unroll
  for (int j2 = 0; j2 < 8; ++j2) acc[j2] = 0.f;
  const unsigned short* fbase = feat + l * 8;
  int j = beg;
  for (; j + 4 <= end; j += 4) {
    int s0 = csr_src[j + 0], s1 = csr_src[j + 1];
    int s2 = csr_src[j + 2], s3 = csr_src[j + 3];
    float q0 = el[s0 * 4 + g], q1 = el[s1 * 4 + g];
    float q2 = el[s2 * 4 + g], q3 = el[s3 * 4 + g];
    u16x8 f0 = *(const u16x8*)(fbase + (size_t)s0 * fstride);
    u16x8 f1 = *(const u16x8*)(fbase + (size_t)s1 * fstride);
    u16x8 f2 = *(const u16x8*)(fbase + (size_t)s2 * fstride);
    u16x8 f3 = *(const u16x8*)(fbase + (size_t)s3 * fstride);
    float e0 = q0 + er_g; e0 = (e0 >= 0.f) ? e0 : 0.2f * e0;
    float e1 = q1 + er_g; e1 = (e1 >= 0.f) ? e1 : 0.2f * e1;
    float e2 = q2 + er_g; e2 = (e2 >= 0.f) ? e2 : 0.2f * e2;
    float e3 = q3 + er_g; e3 = (e3 >= 0.f) ? e3 : 0.2f * e3;
    float p0 = __expf(e0), p1 = __expf(e1);
    float p2 = __expf(e2), p3 = __expf(e3);
    asum += (p0 + p1) + (p2 + p3);
#pragma unroll
    for (int k = 0; k < 8; ++k)
      acc[k] += p0 * bf2f(f0[k]) + p1 * bf2f(f1[k]) + p2 * bf2f(f2[k]) + p3 * bf2f(f3[k]);
  }
  for (; j < end; ++j) {
    int s = csr_src[j];
    float ev = el[s * 4 + g] + er_g;
    ev = (ev >= 0.f) ? ev : 0.2f * ev;
    float p = __expf(ev);
    asum += p;
    u16x8 fv = *(const u16x8*)(fbase + (size_t)s * fstride);
#pragma unroll
    for (int k = 0; k < 8; ++k) acc[k] += p * bf2f(fv[k]);
  }
  float inv = (end > beg) ? 1.f / asum : 1.f;
  u16x8 hv = *(const u16x8*)(hres + (size_t)wid * fstride + l * 8);
  float o[8];
#pragma unroll
  for (int k = 0; k < 8; ++k) o[k] = acc[k] * inv + bf2f(hv[k]);
  if constexpr (!FINAL) {
    u16x8 ob;
#pragma unroll
    for (int k = 0; k < 8; ++k) ob[k] = f2bf(fmaxf(o[k], 0.f));
    *(u16x8*)(hnext + (size_t)wid * 512 + l * 8) = ob;
  } else {
#pragma unroll
    for (int k = 0; k < 8; ++k) {
      float v = o[k];
      v += __shfl_xor(v, 16);
      v += __shfl_xor(v, 32);
      o[k] = v * 0.25f;
    }
    if (g == 0) {
      f32x4 o0 = (f32x4){o[0], o[1], o[2], o[3]};
      f32x4 o1 = (f32x4){o[4], o[5], o[6], o[7]};
      *(f32x4*)(h3 + (size_t)wid * 128 + l * 8) = o0;
      *(f32x4*)(h3 + (size_t)wid * 128 + l * 8 + 4) = o1;
      u16x8 hb;
#pragma unroll
      for (int k = 0; k < 8; ++k) hb[k] = f2bf(o[k]);
      *(u16x8*)(h3b + (size_t)wid * 128 + l * 8) = hb;
    }
  }
}

// ---- fused pair MLP v4: direct-to-register X gather + W in LDS (pre-swizzled) ----
template <int MODE>
__global__ __launch_bounds__(256) void k_pair_mlp(
    const unsigned short* __restrict__ X, const int* __restrict__ ia,
    const int* __restrict__ ib, const unsigned short* __restrict__ WbSwz,
    const float* __restrict__ b1, const float* __restrict__ W2,
    const float* __restrict__ b2, float* __restrict__ out, int npairs) {
  __shared__ __align__(16) unsigned short Ws[128 * 128];  // 32 KB
  const int t = threadIdx.x;
  const int l = t & 63, w = t >> 6;
#pragma unroll
  for (int i = 0; i < 8; ++i)
    gload_lds16(WbSwz + i * 2048 + w * 512 + l * 8, &Ws[i * 2048 + w * 512]);
  const int base = blockIdx.x * 128 + w * 32;
  bf16x8 af[2][4];
#pragma unroll
  for (int m = 0; m < 2; ++m) {
    int e = base + m * 16 + (l & 15);
    if (MODE == 1 && e >= npairs) e = npairs - 1;
    int sa, sb;
    if (MODE == 0) { sa = ia[e]; sb = ib[e]; }
    else           { sa = ia[e]; sb = e / KNN_K; }
    const unsigned short* pa = X + (size_t)sa * 128 + (l >> 4) * 8;
    const unsigned short* pb = X + (size_t)sb * 128 + (l >> 4) * 8;
#pragma unroll
    for (int kk = 0; kk < 4; ++kk) {
      u16x8 av = *(const u16x8*)(pa + kk * 32);
      u16x8 bv = *(const u16x8*)(pb + kk * 32);
      u16x8 xv;
#pragma unroll
      for (int j = 0; j < 8; ++j) xv[j] = f2bf(fabsf(bf2f(av[j]) - bf2f(bv[j])));
      af[m][kk] = *(bf16x8*)&xv;
    }
  }
  __syncthreads();  // W staged (drains vmcnt)
  float part[2][4];
#pragma unroll
  for (int m = 0; m < 2; ++m)
#pragma unroll
    for (int r = 0; r < 4; ++r) part[m][r] = 0.f;
#pragma unroll
  for (int n = 0; n < 8; ++n) {
    int rowv = n * 16 + (l & 15);
    bf16x8 bfr[4];
#pragma unroll
    for (int kk = 0; kk < 4; ++kk) {
      int sg = (kk * 4 + (l >> 4)) ^ (rowv & 15);
      bfr[kk] = *(const bf16x8*)&Ws[rowv * 128 + sg * 8];
    }
    f32x4 acc0 = (f32x4){0.f, 0.f, 0.f, 0.f};
    f32x4 acc1 = (f32x4){0.f, 0.f, 0.f, 0.f};
#pragma unroll
    for (int kk = 0; kk < 4; ++kk) {
      acc0 = __builtin_amdgcn_mfma_f32_16x16x32_bf16(af[0][kk], bfr[kk], acc0, 0, 0, 0);
      acc1 = __builtin_amdgcn_mfma_f32_16x16x32_bf16(af[1][kk], bfr[kk], acc1, 0, 0, 0);
    }
    float bb = b1[rowv], w2v = W2[rowv];
#pragma unroll
    for (int r = 0; r < 4; ++r) {
      part[0][r] += fmaxf(acc0[r] + bb, 0.f) * w2v;
      part[1][r] += fmaxf(acc1[r] + bb, 0.f) * w2v;
    }
  }
#pragma unroll
  for (int d = 1; d < 16; d <<= 1)
#pragma unroll
    for (int m = 0; m < 2; ++m)
#pragma unroll
      for (int r = 0; r < 4; ++r) part[m][r] += __shfl_xor(part[m][r], d);
  if ((l & 15) == 0) {
    int q = l >> 4;
    float b2v = b2[0];
#pragma unroll
    for (int m = 0; m < 2; ++m) {
      int e = base + m * 16 + q * 4;
      f32x4 ov;
#pragma unroll
      for (int r = 0; r < 4; ++r) ov[r] = sigmoidf(part[m][r] + b2v);
      if (e + 3 < npairs) *(f32x4*)(out + e) = ov;
      else {
#pragma unroll
        for (int r = 0; r < 4; ++r) if (e + r < npairs) out[e + r] = ov[r];
      }
    }
  }
}

// ---------------- entity segment sums ----------------
__global__ void k_ent_scatter(const float* __restrict__ h3, const float* __restrict__ pos,
                              const int* __restrict__ entity, float* __restrict__ ent_sum,
                              float* __restrict__ pos_sum, float* __restrict__ cnt) {
  int i = blockIdx.x * blockDim.x + threadIdx.x;
  if (i >= N_NODES * 32) return;
  int n = i >> 5, c = i & 31;
  int e = entity[n];
  f32x4 v = *(const f32x4*)(h3 + (size_t)n * 128 + c * 4);
  atomicAdd(&ent_sum[e * 128 + c * 4 + 0], v[0]);
  atomicAdd(&ent_sum[e * 128 + c * 4 + 1], v[1]);
  atomicAdd(&ent_sum[e * 128 + c * 4 + 2], v[2]);
  atomicAdd(&ent_sum[e * 128 + c * 4 + 3], v[3]);
  if (c == 0) {
    atomicAdd(&pos_sum[e * 2 + 0], pos[n * 2 + 0]);
    atomicAdd(&pos_sum[e * 2 + 1], pos[n * 2 + 1]);
    atomicAdd(&cnt[e], 1.f);
  }
}

__global__ void k_entity_states(const float* __restrict__ ent_sum, const float* __restrict__ We,
                                const float* __restrict__ be, float* __restrict__ es) {
  int i = blockIdx.x * blockDim.x + threadIdx.x;
  if (i >= NENT * 128) return;
  int e = i >> 7, j = i & 127;
  const float* x = ent_sum + (size_t)e * 128;
  const float* wrow = We + (size_t)j * 128;
  float s = be[j];
  for (int k = 0; k < 128; k += 4) {
    f32x4 xv = *(const f32x4*)(x + k);
    f32x4 wv = *(const f32x4*)(wrow + k);
    s += xv[0] * wv[0] + xv[1] * wv[1] + xv[2] * wv[2] + xv[3] * wv[3];
  }
  es[i] = s;
}

__global__ void k_entity_class(const float* __restrict__ es, const float* __restrict__ Wc,
                               const float* __restrict__ bc, float* __restrict__ out) {
  int i = blockIdx.x * blockDim.x + threadIdx.x;
  if (i >= NENT * 4) return;
  int e = i >> 2, c = i & 3;
  const float* x = es + (size_t)e * 128;
  const float* wrow = Wc + (size_t)c * 128;
  float s = bc[c];
  for (int k = 0; k < 128; ++k) s += x[k] * wrow[k];
  out[i] = sigmoidf(s);
}

__global__ void k_entity_pos(const float* __restrict__ pos_sum, const float* __restrict__ cnt,
                             float* __restrict__ outpos, float* __restrict__ wspos) {
  int e = blockIdx.x * blockDim.x + threadIdx.x;
  if (e >= NENT) return;
  float c = fmaxf(cnt[e], 1.f);
  float x = pos_sum[e * 2] / c, y = pos_sum[e * 2 + 1] / c;
  outpos[e * 2] = x; outpos[e * 2 + 1] = y;
  wspos[e * 2] = x; wspos[e * 2 + 1] = y;
}

// ---------------- exact knn (K smallest d2, ties -> smaller index) ----------------
__global__ __launch_bounds__(256) void k_knn(const float* __restrict__ entpos,
                                             int* __restrict__ knn) {
  __shared__ float d2row[NENT];
  __shared__ float rv[256];
  __shared__ int ri[256];
  int i = blockIdx.x, t = threadIdx.x;
  float px = entpos[i * 2], py = entpos[i * 2 + 1];
  for (int j = t; j < NENT; j += 256) {
    float dx = px - entpos[j * 2], dy = py - entpos[j * 2 + 1];
    d2row[j] = __fadd_rn(__fmul_rn(dx, dx), __fmul_rn(dy, dy));
  }
  __syncthreads();
  for (int k = 0; k < KNN_K; ++k) {
    float bv = __builtin_inff(); int bi = 0x7fffffff;
    for (int j = t; j < NENT; j += 256) {
      float v = d2row[j];
      if (v < bv) { bv = v; bi = j; }
    }
    rv[t] = bv; ri[t] = bi;
    __syncthreads();
    for (int s = 128; s > 0; s >>= 1) {
      if (t < s) {
        if (rv[t + s] < rv[t] || (rv[t + s] == rv[t] && ri[t + s] < ri[t])) {
          rv[t] = rv[t + s]; ri[t] = ri[t + s];
        }
      }
      __syncthreads();
    }
    if (t == 0) { knn[i * KNN_K + k] = ri[0]; d2row[ri[0]] = __builtin_inff(); }
    __syncthreads();
  }
}

// =======================================================================
extern "C" void kernel_launch(void* const* d_in, const int* in_sizes, int n_in,
                              void* d_out, int out_size, void* d_ws, size_t ws_size,
                              hipStream_t stream) {
  const float* position = (const float*)d_in[0];
  const float* w_embed  = (const float*)d_in[1];
  const int*   src      = (const int*)d_in[2];
  const int*   dst      = (const int*)d_in[3];
  const int*   entity   = (const int*)d_in[4];
  const float* W1 = (const float*)d_in[5];
  const float* al1 = (const float*)d_in[6];
  const float* ar1 = (const float*)d_in[7];
  const float* Wr1 = (const float*)d_in[8];
  const float* W2 = (const float*)d_in[9];
  const float* al2 = (const float*)d_in[10];
  const float* ar2 = (const float*)d_in[11];
  const float* Wr2 = (const float*)d_in[12];
  const float* W3 = (const float*)d_in[13];
  const float* al3 = (const float*)d_in[14];
  const float* ar3 = (const float*)d_in[15];
  const float* Wr3 = (const float*)d_in[16];
  const float* Wg1 = (const float*)d_in[17];
  const float* bg1 = (const float*)d_in[18];
  const float* Wg2 = (const float*)d_in[19];
  const float* bg2 = (const float*)d_in[20];
  const float* We  = (const float*)d_in[21];
  const float* be  = (const float*)d_in[22];
  const float* Wl1 = (const float*)d_in[23];
  const float* bl1 = (const float*)d_in[24];
  const float* Wl2 = (const float*)d_in[25];
  const float* bl2 = (const float*)d_in[26];
  const float* Wc  = (const float*)d_in[27];
  const float* bc  = (const float*)d_in[28];

  float* out_groups = (float*)d_out;
  float* out_class  = out_groups + N_EDGES;
  float* out_pos    = out_class + NENT * 4;
  float* out_link   = out_pos + NENT * 2;

  char* ws = (char*)d_ws;
  size_t off = 0;
  auto carve = [&](size_t bytes) -> char* {
    char* p = ws + off;
    off = (off + bytes + 255) & ~(size_t)255;
    return p;
  };
  // fused GEMM output: [N, 1024] bf16 — cols 0..511 = feat, 512..1023 = hres
  unsigned short* featC = (unsigned short*)carve((size_t)N_NODES * 1024 * 2);
  unsigned short* hA = (unsigned short*)carve((size_t)N_NODES * 512 * 2);
  unsigned short* hB = (unsigned short*)carve((size_t)N_NODES * 512 * 2);
  unsigned short* wbf1 = (unsigned short*)carve((size_t)1024 * 128 * 2);  // [W1;Wr1]
  unsigned short* wbf2 = (unsigned short*)carve((size_t)1024 * 512 * 2);  // [W2;Wr2]
  unsigned short* wbf3 = (unsigned short*)carve((size_t)1024 * 512 * 2);  // [W3;Wr3]
  unsigned short* wg1b = (unsigned short*)carve(128 * 128 * 2);
  unsigned short* wl1b = (unsigned short*)carve(128 * 128 * 2);
  float* el = (float*)carve((size_t)N_NODES * 4 * 4);   // contiguous with er
  float* er = (float*)carve((size_t)N_NODES * 4 * 4);
  int* indeg = (int*)carve((size_t)N_NODES * 4);
  int* indptr = (int*)carve((size_t)(N_NODES + 1) * 4);
  int* cursor = (int*)carve((size_t)N_NODES * 4);
  int* csr_src = (int*)carve((size_t)N_EDGES * 4);
  float* h3 = (float*)carve((size_t)N_NODES * 128 * 4);
  unsigned short* h3b = (unsigned short*)carve((size_t)N_NODES * 128 * 2);
  float* ent_sum = (float*)carve((size_t)NENT * 128 * 4);
  float* pos_sum = (float*)carve((size_t)NENT * 2 * 4);
  float* cnt = (float*)carve((size_t)NENT * 4);
  float* es = (float*)carve((size_t)NENT * 128 * 4);
  unsigned short* esb = (unsigned short*)carve((size_t)NENT * 128 * 2);
  float* wspos = (float*)carve((size_t)NENT * 2 * 4);
  int* knn = (int*)carve((size_t)NENT * KNN_K * 4);

  const size_t eler_bytes = (size_t)((char*)er - (char*)el) + (size_t)N_NODES * 4 * 4;

  // ---- CSR over dst (shared by all 3 GAT layers) ----
  hipMemsetAsync(indeg, 0, (size_t)N_NODES * 4, stream);
  k_hist<<<(N_EDGES + 255) / 256, 256, 0, stream>>>(dst, indeg);
  k_scan_fast<<<1, 1024, 0, stream>>>(indeg, indptr, cursor);
  k_scatter<<<(N_EDGES + 255) / 256, 256, 0, stream>>>(src, dst, cursor, csr_src);

  k_build_h0<<<(N_NODES * 128 + 255) / 256, 256, 0, stream>>>(position, w_embed, hA);

  // ---- all weight conversions in one launch ----
  k_conv_weights<<<(303104 + 255) / 256, 256, 0, stream>>>(W1, Wr1, W2, Wr2, W3, Wr3, Wg1, Wl1,
                                                           wbf1, wbf2, wbf3, wg1b, wl1b);

  dim3 ggrid((N_NODES + 127) / 128, 8), gblk(256);

  // ---- layer 1 (K=128), fused W|Wr GEMM + el/er epilogue ----
  hipMemsetAsync(el, 0, eler_bytes, stream);
  k_gemm_bt<<<ggrid, gblk, 0, stream>>>(hA, wbf1, featC, N_NODES, 1024, 128, al1, ar1, el, er);
  k_gat_agg<false><<<5000, 256, 0, stream>>>(featC, featC + 512, 1024, el, er, indptr,
                                             csr_src, hB, nullptr, nullptr);

  // ---- layer 2 (K=512) ----
  hipMemsetAsync(el, 0, eler_bytes, stream);
  k_gemm_bt<<<ggrid, gblk, 0, stream>>>(hB, wbf2, featC, N_NODES, 1024, 512, al2, ar2, el, er);
  k_gat_agg<false><<<5000, 256, 0, stream>>>(featC, featC + 512, 1024, el, er, indptr,
                                             csr_src, hA, nullptr, nullptr);

  // ---- layer 3 (K=512, no relu, head-mean) ----
  hipMemsetAsync(el, 0, eler_bytes, stream);
  k_gemm_bt<<<ggrid, gblk, 0, stream>>>(hA, wbf3, featC, N_NODES, 1024, 512, al3, ar3, el, er);
  k_gat_agg<true><<<5000, 256, 0, stream>>>(featC, featC + 512, 1024, el, er, indptr,
                                            csr_src, nullptr, h3, h3b);

  // ---- groups_score (pair MLP v4 on bf16 h3) ----
  k_pair_mlp<0><<<N_EDGES / 128, 256, 0, stream>>>(h3b, src, dst, wg1b, bg1, Wg2, bg2,
                                                   out_groups, N_EDGES);

  // ---- entity path (ent_sum/pos_sum/cnt contiguous -> one memset) ----
  size_t zbytes = (size_t)((char*)cnt - (char*)ent_sum) + NENT * 4;
  hipMemsetAsync(ent_sum, 0, zbytes, stream);
  k_ent_scatter<<<(N_NODES * 32 + 255) / 256, 256, 0, stream>>>(h3, position, entity, ent_sum,
                                                                pos_sum, cnt);
  k_entity_states<<<(NENT * 128 + 255) / 256, 256, 0, stream>>>(ent_sum, We, be, es);
  k_entity_class<<<(NENT * 4 + 255) / 256, 256, 0, stream>>>(es, Wc, bc, out_class);
  k_entity_pos<<<(NENT + 255) / 256, 256, 0, stream>>>(pos_sum, cnt, out_pos, wspos);
  k_knn<<<NENT, 256, 0, stream>>>(wspos, knn);
  k_f2bf<<<(NENT * 128 / 4 + 255) / 256, 256, 0, stream>>>(es, esb, NENT * 128);
  k_pair_mlp<1><<<(NENT * KNN_K + 127) / 128, 256, 0, stream>>>(esb, knn, nullptr, wl1b, bl1,
                                                                Wl2, bl2, out_link,
                                                                NENT * KNN_K);
}

// Round 11
// 456.860 us; speedup vs baseline: 1.0817x; 1.0817x over previous
//
#include <hip/hip_runtime.h>
#include <math.h>

#define N_NODES 20000
#define N_EDGES 320000
#define NENT    2000
#define KNN_K   10

typedef __attribute__((ext_vector_type(4))) float f32x4;
typedef __attribute__((ext_vector_type(8))) short bf16x8;
typedef __attribute__((ext_vector_type(8))) unsigned short u16x8;
typedef __attribute__((ext_vector_type(4))) unsigned short u16x4;

__device__ __forceinline__ unsigned short f2bf(float f) {
  union { float f; unsigned u; } v; v.f = f;
  unsigned r = v.u + 0x7fffu + ((v.u >> 16) & 1u);
  return (unsigned short)(r >> 16);
}
__device__ __forceinline__ float bf2f(unsigned short u) {
  union { unsigned u; float f; } v; v.u = ((unsigned)u) << 16;
  return v.f;
}
__device__ __forceinline__ float sigmoidf(float x) {
  return 1.f / (1.f + __expf(-x));
}
// async global->LDS, 16B per lane; lds dest = wave-uniform base + lane*16
__device__ __forceinline__ void gload_lds16(const unsigned short* g, unsigned short* lds) {
  __builtin_amdgcn_global_load_lds(
      (const __attribute__((address_space(1))) unsigned int*)g,
      (__attribute__((address_space(3))) unsigned int*)lds, 16, 0, 0);
}

// ---------------- h0 = concat(position, w_embed) -> bf16 ----------------
__global__ void k_build_h0(const float* __restrict__ pos, const float* __restrict__ wemb,
                           unsigned short* __restrict__ h0) {
  int i = blockIdx.x * blockDim.x + threadIdx.x;
  if (i >= N_NODES * 128) return;
  int n = i >> 7, c = i & 127;
  float v = (c < 2) ? pos[n * 2 + c] : wemb[n * 126 + (c - 2)];
  h0[i] = f2bf(v);
}

// ---------------- generic f32 -> bf16 (n multiple of 4) ----------------
__global__ void k_f2bf(const float* __restrict__ in, unsigned short* __restrict__ out, int n) {
  int i = blockIdx.x * blockDim.x + threadIdx.x;
  if (i * 4 >= n) return;
  f32x4 v = *(const f32x4*)(in + i * 4);
  u16x4 o;
  o[0] = f2bf(v[0]); o[1] = f2bf(v[1]); o[2] = f2bf(v[2]); o[3] = f2bf(v[3]);
  *(u16x4*)(out + i * 4) = o;
}

// ---- ALL weight conversions in one launch ----
__global__ void k_conv_weights(
    const float* __restrict__ W1, const float* __restrict__ Wr1,
    const float* __restrict__ W2, const float* __restrict__ Wr2,
    const float* __restrict__ W3, const float* __restrict__ Wr3,
    const float* __restrict__ Wg1, const float* __restrict__ Wl1,
    unsigned short* __restrict__ wbf1, unsigned short* __restrict__ wbf2,
    unsigned short* __restrict__ wbf3, unsigned short* __restrict__ wg1b,
    unsigned short* __restrict__ wl1b) {
  int i4 = (blockIdx.x * blockDim.x + threadIdx.x) * 4;
  const float* src;
  unsigned short* dst;
  if (i4 < 131072) {
    src = (i4 < 65536) ? (W1 + i4) : (Wr1 + i4 - 65536);
    dst = wbf1 + i4;
  } else if ((i4 -= 131072) < 524288) {
    src = (i4 < 262144) ? (W2 + i4) : (Wr2 + i4 - 262144);
    dst = wbf2 + i4;
  } else if ((i4 -= 524288) < 524288) {
    src = (i4 < 262144) ? (W3 + i4) : (Wr3 + i4 - 262144);
    dst = wbf3 + i4;
  } else if ((i4 -= 524288) < 32768) {
    // swizzled 128x128: 4 consecutive k stay contiguous after swizzle
    const float* W = (i4 < 16384) ? Wg1 : Wl1;
    unsigned short* O = (i4 < 16384) ? wg1b : wl1b;
    int ii = i4 & 16383;
    int row = ii >> 7, k = ii & 127;
    int sg = (k >> 3) ^ (row & 15);
    src = W + ii;
    dst = O + row * 128 + sg * 8 + (k & 7);
  } else {
    return;
  }
  f32x4 v = *(const f32x4*)src;
  u16x4 o;
  o[0] = f2bf(v[0]); o[1] = f2bf(v[1]); o[2] = f2bf(v[2]); o[3] = f2bf(v[3]);
  *(u16x4*)dst = o;
}

// ------- bf16 MFMA GEMM: C[M,Nc] = A[M,K] * B[Nc,K]^T, bf16 out, stride Nc -------
__global__ __launch_bounds__(256) void k_gemm_bt(
    const unsigned short* __restrict__ A, const unsigned short* __restrict__ B,
    unsigned short* __restrict__ C, int M, int Nc, int K) {
  __shared__ __align__(16) unsigned short As[128 * 64];
  __shared__ __align__(16) unsigned short Bs[128 * 64];
  const int bm = blockIdx.x * 128, bn = blockIdx.y * 128;
  const int t = threadIdx.x;
  const int l = t & 63, w = t >> 6;
  const int wr = w >> 1, wc = w & 1;
  f32x4 acc[4][4];
#pragma unroll
  for (int m = 0; m < 4; ++m)
#pragma unroll
    for (int n = 0; n < 4; ++n) acc[m][n] = (f32x4){0.f, 0.f, 0.f, 0.f};

  for (int kb = 0; kb < K; kb += 64) {
    __syncthreads();
#pragma unroll
    for (int i = 0; i < 4; ++i) {
      int c = t + 256 * i;         // 1024 16B-chunks per tile
      int row = c >> 3, cc = c & 7;
      int scc = cc ^ (row & 7);    // pre-swizzled SOURCE granule (read side keeps same XOR)
      int ar = bm + row; if (ar > M - 1) ar = M - 1;
      gload_lds16(A + (size_t)ar * K + kb + scc * 8, &As[(size_t)(w * 64 + 256 * i) * 8]);
      gload_lds16(B + (size_t)(bn + row) * K + kb + scc * 8,
                  &Bs[(size_t)(w * 64 + 256 * i) * 8]);
    }
    __syncthreads();
#pragma unroll
    for (int kk = 0; kk < 2; ++kk) {
      bf16x8 af[4], bfr[4];
#pragma unroll
      for (int m = 0; m < 4; ++m) {
        int row = wr * 64 + m * 16 + (l & 15);
        int g = (kk * 4 + (l >> 4)) ^ (row & 7);
        af[m] = *(const bf16x8*)&As[row * 64 + g * 8];
      }
#pragma unroll
      for (int n = 0; n < 4; ++n) {
        int row = wc * 64 + n * 16 + (l & 15);
        int g = (kk * 4 + (l >> 4)) ^ (row & 7);
        bfr[n] = *(const bf16x8*)&Bs[row * 64 + g * 8];
      }
#pragma unroll
      for (int m = 0; m < 4; ++m)
#pragma unroll
        for (int n = 0; n < 4; ++n)
          acc[m][n] = __builtin_amdgcn_mfma_f32_16x16x32_bf16(af[m], bfr[n], acc[m][n], 0, 0, 0);
    }
  }
#pragma unroll
  for (int m = 0; m < 4; ++m) {
    int r0 = bm + wr * 64 + m * 16 + ((l >> 4) << 2);
#pragma unroll
    for (int n = 0; n < 4; ++n) {
      int c0 = bn + wc * 64 + n * 16 + (l & 15);
#pragma unroll
      for (int r = 0; r < 4; ++r) {
        int row = r0 + r;
        if (row < M) C[(size_t)row * Nc + c0] = f2bf(acc[m][n][r]);
      }
    }
  }
}

// ---------------- el/er: per (node, head) dot(feat, al/ar) ----------------
__global__ void k_el_er(const unsigned short* __restrict__ feat, int fstride,
                        const float* __restrict__ al, const float* __restrict__ ar,
                        float* __restrict__ el, float* __restrict__ er) {
  int wid = (blockIdx.x * blockDim.x + threadIdx.x) >> 6;
  if (wid >= N_NODES) return;
  int l = threadIdx.x & 63;
  int g = l >> 4, q = l & 15;
  u16x8 fv = *(const u16x8*)(feat + (size_t)wid * fstride + l * 8);
  const float* alp = al + g * 128 + q * 8;
  const float* arp = ar + g * 128 + q * 8;
  float sl = 0.f, sr = 0.f;
#pragma unroll
  for (int j = 0; j < 8; ++j) { float f = bf2f(fv[j]); sl += f * alp[j]; sr += f * arp[j]; }
#pragma unroll
  for (int d = 1; d < 16; d <<= 1) { sl += __shfl_xor(sl, d); sr += __shfl_xor(sr, d); }
  if (q == 0) { el[wid * 4 + g] = sl; er[wid * 4 + g] = sr; }
}

// ---------------- CSR build ----------------
__global__ void k_hist(const int* __restrict__ dst, int* __restrict__ indeg) {
  int e = blockIdx.x * blockDim.x + threadIdx.x;
  if (e < N_EDGES) atomicAdd(&indeg[dst[e]], 1);
}

__global__ __launch_bounds__(1024) void k_scan_fast(const int* __restrict__ indeg,
                                                    int* __restrict__ indptr,
                                                    int* __restrict__ cursor) {
  __shared__ int wsum[16];
  const int t = threadIdx.x;
  const int l = t & 63, w = t >> 6;
  const int CH = 20;  // 1024*20 >= 20000
  int base = t * CH;
  int vals[CH];
  int s = 0;
#pragma unroll
  for (int i = 0; i < CH; ++i) {
    int idx = base + i;
    int v = (idx < N_NODES) ? indeg[idx] : 0;
    vals[i] = v;
    s += v;
  }
  int ss = s;
#pragma unroll
  for (int d = 1; d < 64; d <<= 1) { int o = __shfl_up(ss, d); if (l >= d) ss += o; }
  if (l == 63) wsum[w] = ss;
  __syncthreads();
  if (t < 16) {
    int v = wsum[t];
#pragma unroll
    for (int d = 1; d < 16; d <<= 1) { int o = __shfl_up(v, d); if (t >= d) v += o; }
    wsum[t] = v;
  }
  __syncthreads();
  int run = ((w > 0) ? wsum[w - 1] : 0) + ss - s;
  if (t == 0) indptr[0] = 0;
#pragma unroll
  for (int i = 0; i < CH; ++i) {
    int idx = base + i;
    if (idx < N_NODES) {
      cursor[idx] = run;
      run += vals[i];
      indptr[idx + 1] = run;
    }
  }
}

__global__ void k_scatter(const int* __restrict__ src, const int* __restrict__ dst,
                          int* __restrict__ cursor, int* __restrict__ csr_src) {
  int e = blockIdx.x * blockDim.x + threadIdx.x;
  if (e < N_EDGES) {
    int p = atomicAdd(&cursor[dst[e]], 1);
    csr_src[p] = src[e];
  }
}

// ---------------- GAT edge-softmax + aggregation (wave per dst node) ----------------
// no-max softmax (alpha invariant to shift; |e| << 88 so exp is safe),
// 4-deep unrolled gather loop
template <bool FINAL>
__global__ void k_gat_agg(const unsigned short* __restrict__ feat,
                          const unsigned short* __restrict__ hres, int fstride,
                          const float* __restrict__ el, const float* __restrict__ er,
                          const int* __restrict__ indptr, const int* __restrict__ csr_src,
                          unsigned short* __restrict__ hnext, float* __restrict__ h3,
                          unsigned short* __restrict__ h3b) {
  int wid = (blockIdx.x * blockDim.x + threadIdx.x) >> 6;
  if (wid >= N_NODES) return;
  int l = threadIdx.x & 63;
  int g = l >> 4;
  int beg = indptr[wid], end = indptr[wid + 1];
  float er_g = er[wid * 4 + g];
  float asum = 0.f;
  float acc[8];
#pragma unroll
  for (int j2 = 0; j2 < 8; ++j2) acc[j2] = 0.f;
  const unsigned short* fbase = feat + l * 8;
  int j = beg;
  for (; j + 4 <= end; j += 4) {
    int s0 = csr_src[j + 0], s1 = csr_src[j + 1];
    int s2 = csr_src[j + 2], s3 = csr_src[j + 3];
    float q0 = el[s0 * 4 + g], q1 = el[s1 * 4 + g];
    float q2 = el[s2 * 4 + g], q3 = el[s3 * 4 + g];
    u16x8 f0 = *(const u16x8*)(fbase + (size_t)s0 * fstride);
    u16x8 f1 = *(const u16x8*)(fbase + (size_t)s1 * fstride);
    u16x8 f2 = *(const u16x8*)(fbase + (size_t)s2 * fstride);
    u16x8 f3 = *(const u16x8*)(fbase + (size_t)s3 * fstride);
    float e0 = q0 + er_g; e0 = (e0 >= 0.f) ? e0 : 0.2f * e0;
    float e1 = q1 + er_g; e1 = (e1 >= 0.f) ? e1 : 0.2f * e1;
    float e2 = q2 + er_g; e2 = (e2 >= 0.f) ? e2 : 0.2f * e2;
    float e3 = q3 + er_g; e3 = (e3 >= 0.f) ? e3 : 0.2f * e3;
    float p0 = __expf(e0), p1 = __expf(e1);
    float p2 = __expf(e2), p3 = __expf(e3);
    asum += (p0 + p1) + (p2 + p3);
#pragma unroll
    for (int k = 0; k < 8; ++k)
      acc[k] += p0 * bf2f(f0[k]) + p1 * bf2f(f1[k]) + p2 * bf2f(f2[k]) + p3 * bf2f(f3[k]);
  }
  for (; j < end; ++j) {
    int s = csr_src[j];
    float ev = el[s * 4 + g] + er_g;
    ev = (ev >= 0.f) ? ev : 0.2f * ev;
    float p = __expf(ev);
    asum += p;
    u16x8 fv = *(const u16x8*)(fbase + (size_t)s * fstride);
#pragma unroll
    for (int k = 0; k < 8; ++k) acc[k] += p * bf2f(fv[k]);
  }
  float inv = (end > beg) ? 1.f / asum : 1.f;
  u16x8 hv = *(const u16x8*)(hres + (size_t)wid * fstride + l * 8);
  float o[8];
#pragma unroll
  for (int k = 0; k < 8; ++k) o[k] = acc[k] * inv + bf2f(hv[k]);
  if constexpr (!FINAL) {
    u16x8 ob;
#pragma unroll
    for (int k = 0; k < 8; ++k) ob[k] = f2bf(fmaxf(o[k], 0.f));
    *(u16x8*)(hnext + (size_t)wid * 512 + l * 8) = ob;
  } else {
#pragma unroll
    for (int k = 0; k < 8; ++k) {
      float v = o[k];
      v += __shfl_xor(v, 16);
      v += __shfl_xor(v, 32);
      o[k] = v * 0.25f;
    }
    if (g == 0) {
      f32x4 o0 = (f32x4){o[0], o[1], o[2], o[3]};
      f32x4 o1 = (f32x4){o[4], o[5], o[6], o[7]};
      *(f32x4*)(h3 + (size_t)wid * 128 + l * 8) = o0;
      *(f32x4*)(h3 + (size_t)wid * 128 + l * 8 + 4) = o1;
      u16x8 hb;
#pragma unroll
      for (int k = 0; k < 8; ++k) hb[k] = f2bf(o[k]);
      *(u16x8*)(h3b + (size_t)wid * 128 + l * 8) = hb;
    }
  }
}

// ---- fused pair MLP v4: direct-to-register X gather + W in LDS (pre-swizzled) ----
template <int MODE>
__global__ __launch_bounds__(256) void k_pair_mlp(
    const unsigned short* __restrict__ X, const int* __restrict__ ia,
    const int* __restrict__ ib, const unsigned short* __restrict__ WbSwz,
    const float* __restrict__ b1, const float* __restrict__ W2,
    const float* __restrict__ b2, float* __restrict__ out, int npairs) {
  __shared__ __align__(16) unsigned short Ws[128 * 128];  // 32 KB
  const int t = threadIdx.x;
  const int l = t & 63, w = t >> 6;
#pragma unroll
  for (int i = 0; i < 8; ++i)
    gload_lds16(WbSwz + i * 2048 + w * 512 + l * 8, &Ws[i * 2048 + w * 512]);
  const int base = blockIdx.x * 128 + w * 32;
  bf16x8 af[2][4];
#pragma unroll
  for (int m = 0; m < 2; ++m) {
    int e = base + m * 16 + (l & 15);
    if (MODE == 1 && e >= npairs) e = npairs - 1;
    int sa, sb;
    if (MODE == 0) { sa = ia[e]; sb = ib[e]; }
    else           { sa = ia[e]; sb = e / KNN_K; }
    const unsigned short* pa = X + (size_t)sa * 128 + (l >> 4) * 8;
    const unsigned short* pb = X + (size_t)sb * 128 + (l >> 4) * 8;
#pragma unroll
    for (int kk = 0; kk < 4; ++kk) {
      u16x8 av = *(const u16x8*)(pa + kk * 32);
      u16x8 bv = *(const u16x8*)(pb + kk * 32);
      u16x8 xv;
#pragma unroll
      for (int j = 0; j < 8; ++j) xv[j] = f2bf(fabsf(bf2f(av[j]) - bf2f(bv[j])));
      af[m][kk] = *(bf16x8*)&xv;
    }
  }
  __syncthreads();  // W staged (drains vmcnt)
  float part[2][4];
#pragma unroll
  for (int m = 0; m < 2; ++m)
#pragma unroll
    for (int r = 0; r < 4; ++r) part[m][r] = 0.f;
#pragma unroll
  for (int n = 0; n < 8; ++n) {
    int rowv = n * 16 + (l & 15);
    bf16x8 bfr[4];
#pragma unroll
    for (int kk = 0; kk < 4; ++kk) {
      int sg = (kk * 4 + (l >> 4)) ^ (rowv & 15);
      bfr[kk] = *(const bf16x8*)&Ws[rowv * 128 + sg * 8];
    }
    f32x4 acc0 = (f32x4){0.f, 0.f, 0.f, 0.f};
    f32x4 acc1 = (f32x4){0.f, 0.f, 0.f, 0.f};
#pragma unroll
    for (int kk = 0; kk < 4; ++kk) {
      acc0 = __builtin_amdgcn_mfma_f32_16x16x32_bf16(af[0][kk], bfr[kk], acc0, 0, 0, 0);
      acc1 = __builtin_amdgcn_mfma_f32_16x16x32_bf16(af[1][kk], bfr[kk], acc1, 0, 0, 0);
    }
    float bb = b1[rowv], w2v = W2[rowv];
#pragma unroll
    for (int r = 0; r < 4; ++r) {
      part[0][r] += fmaxf(acc0[r] + bb, 0.f) * w2v;
      part[1][r] += fmaxf(acc1[r] + bb, 0.f) * w2v;
    }
  }
#pragma unroll
  for (int d = 1; d < 16; d <<= 1)
#pragma unroll
    for (int m = 0; m < 2; ++m)
#pragma unroll
      for (int r = 0; r < 4; ++r) part[m][r] += __shfl_xor(part[m][r], d);
  if ((l & 15) == 0) {
    int q = l >> 4;
    float b2v = b2[0];
#pragma unroll
    for (int m = 0; m < 2; ++m) {
      int e = base + m * 16 + q * 4;
      f32x4 ov;
#pragma unroll
      for (int r = 0; r < 4; ++r) ov[r] = sigmoidf(part[m][r] + b2v);
      if (e + 3 < npairs) *(f32x4*)(out + e) = ov;
      else {
#pragma unroll
        for (int r = 0; r < 4; ++r) if (e + r < npairs) out[e + r] = ov[r];
      }
    }
  }
}

// ---------------- entity segment sums ----------------
__global__ void k_ent_scatter(const float* __restrict__ h3, const float* __restrict__ pos,
                              const int* __restrict__ entity, float* __restrict__ ent_sum,
                              float* __restrict__ pos_sum, float* __restrict__ cnt) {
  int i = blockIdx.x * blockDim.x + threadIdx.x;
  if (i >= N_NODES * 32) return;
  int n = i >> 5, c = i & 31;
  int e = entity[n];
  f32x4 v = *(const f32x4*)(h3 + (size_t)n * 128 + c * 4);
  atomicAdd(&ent_sum[e * 128 + c * 4 + 0], v[0]);
  atomicAdd(&ent_sum[e * 128 + c * 4 + 1], v[1]);
  atomicAdd(&ent_sum[e * 128 + c * 4 + 2], v[2]);
  atomicAdd(&ent_sum[e * 128 + c * 4 + 3], v[3]);
  if (c == 0) {
    atomicAdd(&pos_sum[e * 2 + 0], pos[n * 2 + 0]);
    atomicAdd(&pos_sum[e * 2 + 1], pos[n * 2 + 1]);
    atomicAdd(&cnt[e], 1.f);
  }
}

__global__ void k_entity_states(const float* __restrict__ ent_sum, const float* __restrict__ We,
                                const float* __restrict__ be, float* __restrict__ es) {
  int i = blockIdx.x * blockDim.x + threadIdx.x;
  if (i >= NENT * 128) return;
  int e = i >> 7, j = i & 127;
  const float* x = ent_sum + (size_t)e * 128;
  const float* wrow = We + (size_t)j * 128;
  float s = be[j];
  for (int k = 0; k < 128; k += 4) {
    f32x4 xv = *(const f32x4*)(x + k);
    f32x4 wv = *(const f32x4*)(wrow + k);
    s += xv[0] * wv[0] + xv[1] * wv[1] + xv[2] * wv[2] + xv[3] * wv[3];
  }
  es[i] = s;
}

__global__ void k_entity_class(const float* __restrict__ es, const float* __restrict__ Wc,
                               const float* __restrict__ bc, float* __restrict__ out) {
  int i = blockIdx.x * blockDim.x + threadIdx.x;
  if (i >= NENT * 4) return;
  int e = i >> 2, c = i & 3;
  const float* x = es + (size_t)e * 128;
  const float* wrow = Wc + (size_t)c * 128;
  float s = bc[c];
  for (int k = 0; k < 128; ++k) s += x[k] * wrow[k];
  out[i] = sigmoidf(s);
}

__global__ void k_entity_pos(const float* __restrict__ pos_sum, const float* __restrict__ cnt,
                             float* __restrict__ outpos, float* __restrict__ wspos) {
  int e = blockIdx.x * blockDim.x + threadIdx.x;
  if (e >= NENT) return;
  float c = fmaxf(cnt[e], 1.f);
  float x = pos_sum[e * 2] / c, y = pos_sum[e * 2 + 1] / c;
  outpos[e * 2] = x; outpos[e * 2 + 1] = y;
  wspos[e * 2] = x; wspos[e * 2 + 1] = y;
}

// ---------------- exact knn (K smallest d2, ties -> smaller index) ----------------
__global__ __launch_bounds__(256) void k_knn(const float* __restrict__ entpos,
                                             int* __restrict__ knn) {
  __shared__ float d2row[NENT];
  __shared__ float rv[256];
  __shared__ int ri[256];
  int i = blockIdx.x, t = threadIdx.x;
  float px = entpos[i * 2], py = entpos[i * 2 + 1];
  for (int j = t; j < NENT; j += 256) {
    float dx = px - entpos[j * 2], dy = py - entpos[j * 2 + 1];
    d2row[j] = __fadd_rn(__fmul_rn(dx, dx), __fmul_rn(dy, dy));
  }
  __syncthreads();
  for (int k = 0; k < KNN_K; ++k) {
    float bv = __builtin_inff(); int bi = 0x7fffffff;
    for (int j = t; j < NENT; j += 256) {
      float v = d2row[j];
      if (v < bv) { bv = v; bi = j; }
    }
    rv[t] = bv; ri[t] = bi;
    __syncthreads();
    for (int s = 128; s > 0; s >>= 1) {
      if (t < s) {
        if (rv[t + s] < rv[t] || (rv[t + s] == rv[t] && ri[t + s] < ri[t])) {
          rv[t] = rv[t + s]; ri[t] = ri[t + s];
        }
      }
      __syncthreads();
    }
    if (t == 0) { knn[i * KNN_K + k] = ri[0]; d2row[ri[0]] = __builtin_inff(); }
    __syncthreads();
  }
}

// =======================================================================
extern "C" void kernel_launch(void* const* d_in, const int* in_sizes, int n_in,
                              void* d_out, int out_size, void* d_ws, size_t ws_size,
                              hipStream_t stream) {
  const float* position = (const float*)d_in[0];
  const float* w_embed  = (const float*)d_in[1];
  const int*   src      = (const int*)d_in[2];
  const int*   dst      = (const int*)d_in[3];
  const int*   entity   = (const int*)d_in[4];
  const float* W1 = (const float*)d_in[5];
  const float* al1 = (const float*)d_in[6];
  const float* ar1 = (const float*)d_in[7];
  const float* Wr1 = (const float*)d_in[8];
  const float* W2 = (const float*)d_in[9];
  const float* al2 = (const float*)d_in[10];
  const float* ar2 = (const float*)d_in[11];
  const float* Wr2 = (const float*)d_in[12];
  const float* W3 = (const float*)d_in[13];
  const float* al3 = (const float*)d_in[14];
  const float* ar3 = (const float*)d_in[15];
  const float* Wr3 = (const float*)d_in[16];
  const float* Wg1 = (const float*)d_in[17];
  const float* bg1 = (const float*)d_in[18];
  const float* Wg2 = (const float*)d_in[19];
  const float* bg2 = (const float*)d_in[20];
  const float* We  = (const float*)d_in[21];
  const float* be  = (const float*)d_in[22];
  const float* Wl1 = (const float*)d_in[23];
  const float* bl1 = (const float*)d_in[24];
  const float* Wl2 = (const float*)d_in[25];
  const float* bl2 = (const float*)d_in[26];
  const float* Wc  = (const float*)d_in[27];
  const float* bc  = (const float*)d_in[28];

  float* out_groups = (float*)d_out;
  float* out_class  = out_groups + N_EDGES;
  float* out_pos    = out_class + NENT * 4;
  float* out_link   = out_pos + NENT * 2;

  char* ws = (char*)d_ws;
  size_t off = 0;
  auto carve = [&](size_t bytes) -> char* {
    char* p = ws + off;
    off = (off + bytes + 255) & ~(size_t)255;
    return p;
  };
  // fused GEMM output: [N, 1024] bf16 — cols 0..511 = feat, 512..1023 = hres
  unsigned short* featC = (unsigned short*)carve((size_t)N_NODES * 1024 * 2);
  unsigned short* hA = (unsigned short*)carve((size_t)N_NODES * 512 * 2);
  unsigned short* hB = (unsigned short*)carve((size_t)N_NODES * 512 * 2);
  unsigned short* wbf1 = (unsigned short*)carve((size_t)1024 * 128 * 2);  // [W1;Wr1]
  unsigned short* wbf2 = (unsigned short*)carve((size_t)1024 * 512 * 2);  // [W2;Wr2]
  unsigned short* wbf3 = (unsigned short*)carve((size_t)1024 * 512 * 2);  // [W3;Wr3]
  unsigned short* wg1b = (unsigned short*)carve(128 * 128 * 2);
  unsigned short* wl1b = (unsigned short*)carve(128 * 128 * 2);
  float* el = (float*)carve((size_t)N_NODES * 4 * 4);
  float* er = (float*)carve((size_t)N_NODES * 4 * 4);
  int* indeg = (int*)carve((size_t)N_NODES * 4);
  int* indptr = (int*)carve((size_t)(N_NODES + 1) * 4);
  int* cursor = (int*)carve((size_t)N_NODES * 4);
  int* csr_src = (int*)carve((size_t)N_EDGES * 4);
  float* h3 = (float*)carve((size_t)N_NODES * 128 * 4);
  unsigned short* h3b = (unsigned short*)carve((size_t)N_NODES * 128 * 2);
  float* ent_sum = (float*)carve((size_t)NENT * 128 * 4);
  float* pos_sum = (float*)carve((size_t)NENT * 2 * 4);
  float* cnt = (float*)carve((size_t)NENT * 4);
  float* es = (float*)carve((size_t)NENT * 128 * 4);
  unsigned short* esb = (unsigned short*)carve((size_t)NENT * 128 * 2);
  float* wspos = (float*)carve((size_t)NENT * 2 * 4);
  int* knn = (int*)carve((size_t)NENT * KNN_K * 4);

  // ---- CSR over dst (shared by all 3 GAT layers) ----
  hipMemsetAsync(indeg, 0, (size_t)N_NODES * 4, stream);
  k_hist<<<(N_EDGES + 255) / 256, 256, 0, stream>>>(dst, indeg);
  k_scan_fast<<<1, 1024, 0, stream>>>(indeg, indptr, cursor);
  k_scatter<<<(N_EDGES + 255) / 256, 256, 0, stream>>>(src, dst, cursor, csr_src);

  k_build_h0<<<(N_NODES * 128 + 255) / 256, 256, 0, stream>>>(position, w_embed, hA);

  // ---- all weight conversions in one launch ----
  k_conv_weights<<<(303104 + 255) / 256, 256, 0, stream>>>(W1, Wr1, W2, Wr2, W3, Wr3, Wg1, Wl1,
                                                           wbf1, wbf2, wbf3, wg1b, wl1b);

  dim3 ggrid((N_NODES + 127) / 128, 8), gblk(256);

  // ---- layer 1 (K=128), fused W|Wr GEMM ----
  k_gemm_bt<<<ggrid, gblk, 0, stream>>>(hA, wbf1, featC, N_NODES, 1024, 128);
  k_el_er<<<5000, 256, 0, stream>>>(featC, 1024, al1, ar1, el, er);
  k_gat_agg<false><<<5000, 256, 0, stream>>>(featC, featC + 512, 1024, el, er, indptr,
                                             csr_src, hB, nullptr, nullptr);

  // ---- layer 2 (K=512) ----
  k_gemm_bt<<<ggrid, gblk, 0, stream>>>(hB, wbf2, featC, N_NODES, 1024, 512);
  k_el_er<<<5000, 256, 0, stream>>>(featC, 1024, al2, ar2, el, er);
  k_gat_agg<false><<<5000, 256, 0, stream>>>(featC, featC + 512, 1024, el, er, indptr,
                                             csr_src, hA, nullptr, nullptr);

  // ---- layer 3 (K=512, no relu, head-mean) ----
  k_gemm_bt<<<ggrid, gblk, 0, stream>>>(hA, wbf3, featC, N_NODES, 1024, 512);
  k_el_er<<<5000, 256, 0, stream>>>(featC, 1024, al3, ar3, el, er);
  k_gat_agg<true><<<5000, 256, 0, stream>>>(featC, featC + 512, 1024, el, er, indptr,
                                            csr_src, nullptr, h3, h3b);

  // ---- groups_score (pair MLP v4 on bf16 h3) ----
  k_pair_mlp<0><<<N_EDGES / 128, 256, 0, stream>>>(h3b, src, dst, wg1b, bg1, Wg2, bg2,
                                                   out_groups, N_EDGES);

  // ---- entity path (ent_sum/pos_sum/cnt contiguous -> one memset) ----
  size_t zbytes = (size_t)((char*)cnt - (char*)ent_sum) + NENT * 4;
  hipMemsetAsync(ent_sum, 0, zbytes, stream);
  k_ent_scatter<<<(N_NODES * 32 + 255) / 256, 256, 0, stream>>>(h3, position, entity, ent_sum,
                                                                pos_sum, cnt);
  k_entity_states<<<(NENT * 128 + 255) / 256, 256, 0, stream>>>(ent_sum, We, be, es);
  k_entity_class<<<(NENT * 4 + 255) / 256, 256, 0, stream>>>(es, Wc, bc, out_class);
  k_entity_pos<<<(NENT + 255) / 256, 256, 0, stream>>>(pos_sum, cnt, out_pos, wspos);
  k_knn<<<NENT, 256, 0, stream>>>(wspos, knn);
  k_f2bf<<<(NENT * 128 / 4 + 255) / 256, 256, 0, stream>>>(es, esb, NENT * 128);
  k_pair_mlp<1><<<(NENT * KNN_K + 127) / 128, 256, 0, stream>>>(esb, knn, nullptr, wl1b, bl1,
                                                                Wl2, bl2, out_link,
                                                                NENT * KNN_K);
}

// Round 12
// 441.034 us; speedup vs baseline: 1.1205x; 1.0359x over previous
//
#include <hip/hip_runtime.h>
#include <math.h>

#define N_NODES 20000
#define N_EDGES 320000
#define NENT    2000
#define KNN_K   10

typedef __attribute__((ext_vector_type(4))) float f32x4;
typedef __attribute__((ext_vector_type(8))) short bf16x8;
typedef __attribute__((ext_vector_type(8))) unsigned short u16x8;
typedef __attribute__((ext_vector_type(4))) unsigned short u16x4;

__device__ __forceinline__ unsigned short f2bf(float f) {
  union { float f; unsigned u; } v; v.f = f;
  unsigned r = v.u + 0x7fffu + ((v.u >> 16) & 1u);
  return (unsigned short)(r >> 16);
}
__device__ __forceinline__ float bf2f(unsigned short u) {
  union { unsigned u; float f; } v; v.u = ((unsigned)u) << 16;
  return v.f;
}
__device__ __forceinline__ float sigmoidf(float x) {
  return 1.f / (1.f + __expf(-x));
}
// async global->LDS, 16B per lane; lds dest = wave-uniform base + lane*16
__device__ __forceinline__ void gload_lds16(const unsigned short* g, unsigned short* lds) {
  __builtin_amdgcn_global_load_lds(
      (const __attribute__((address_space(1))) unsigned int*)g,
      (__attribute__((address_space(3))) unsigned int*)lds, 16, 0, 0);
}

// ---------------- h0 = concat(position, w_embed) -> bf16 ----------------
__global__ void k_build_h0(const float* __restrict__ pos, const float* __restrict__ wemb,
                           unsigned short* __restrict__ h0) {
  int i = blockIdx.x * blockDim.x + threadIdx.x;
  if (i >= N_NODES * 128) return;
  int n = i >> 7, c = i & 127;
  float v = (c < 2) ? pos[n * 2 + c] : wemb[n * 126 + (c - 2)];
  h0[i] = f2bf(v);
}

// ---------------- generic f32 -> bf16 (n multiple of 4) ----------------
__global__ void k_f2bf(const float* __restrict__ in, unsigned short* __restrict__ out, int n) {
  int i = blockIdx.x * blockDim.x + threadIdx.x;
  if (i * 4 >= n) return;
  f32x4 v = *(const f32x4*)(in + i * 4);
  u16x4 o;
  o[0] = f2bf(v[0]); o[1] = f2bf(v[1]); o[2] = f2bf(v[2]); o[3] = f2bf(v[3]);
  *(u16x4*)(out + i * 4) = o;
}

// ---- ALL weight conversions in one launch ----
__global__ void k_conv_weights(
    const float* __restrict__ W1, const float* __restrict__ Wr1,
    const float* __restrict__ W2, const float* __restrict__ Wr2,
    const float* __restrict__ W3, const float* __restrict__ Wr3,
    const float* __restrict__ Wg1, const float* __restrict__ Wl1,
    unsigned short* __restrict__ wbf1, unsigned short* __restrict__ wbf2,
    unsigned short* __restrict__ wbf3, unsigned short* __restrict__ wg1b,
    unsigned short* __restrict__ wl1b) {
  int i4 = (blockIdx.x * blockDim.x + threadIdx.x) * 4;
  const float* src;
  unsigned short* dst;
  if (i4 < 131072) {
    src = (i4 < 65536) ? (W1 + i4) : (Wr1 + i4 - 65536);
    dst = wbf1 + i4;
  } else if ((i4 -= 131072) < 524288) {
    src = (i4 < 262144) ? (W2 + i4) : (Wr2 + i4 - 262144);
    dst = wbf2 + i4;
  } else if ((i4 -= 524288) < 524288) {
    src = (i4 < 262144) ? (W3 + i4) : (Wr3 + i4 - 262144);
    dst = wbf3 + i4;
  } else if ((i4 -= 524288) < 32768) {
    // swizzled 128x128: 4 consecutive k stay contiguous after swizzle
    const float* W = (i4 < 16384) ? Wg1 : Wl1;
    unsigned short* O = (i4 < 16384) ? wg1b : wl1b;
    int ii = i4 & 16383;
    int row = ii >> 7, k = ii & 127;
    int sg = (k >> 3) ^ (row & 15);
    src = W + ii;
    dst = O + row * 128 + sg * 8 + (k & 7);
  } else {
    return;
  }
  f32x4 v = *(const f32x4*)src;
  u16x4 o;
  o[0] = f2bf(v[0]); o[1] = f2bf(v[1]); o[2] = f2bf(v[2]); o[3] = f2bf(v[3]);
  *(u16x4*)dst = o;
}

// ------- bf16 MFMA GEMM: C[M,Nc] = A[M,K] * B[Nc,K]^T, bf16 out, stride Nc -------
// 1D grid, XCD-grouped decomposition: the 8 bn-blocks of one bm share id%8
// (one XCD) so the A-panel is fetched once per XCD instead of 8x.
__global__ __launch_bounds__(256) void k_gemm_bt(
    const unsigned short* __restrict__ A, const unsigned short* __restrict__ B,
    unsigned short* __restrict__ C, int M, int Nc, int K, int nbm) {
  const int id = blockIdx.x;
  const int bm128 = (id & 7) + 8 * (id >> 6);
  const int bn128 = (id >> 3) & 7;
  if (bm128 >= nbm) return;  // uniform exit before any barrier
  __shared__ __align__(16) unsigned short As[128 * 64];
  __shared__ __align__(16) unsigned short Bs[128 * 64];
  const int bm = bm128 * 128, bn = bn128 * 128;
  const int t = threadIdx.x;
  const int l = t & 63, w = t >> 6;
  const int wr = w >> 1, wc = w & 1;
  f32x4 acc[4][4];
#pragma unroll
  for (int m = 0; m < 4; ++m)
#pragma unroll
    for (int n = 0; n < 4; ++n) acc[m][n] = (f32x4){0.f, 0.f, 0.f, 0.f};

  for (int kb = 0; kb < K; kb += 64) {
    __syncthreads();
#pragma unroll
    for (int i = 0; i < 4; ++i) {
      int c = t + 256 * i;         // 1024 16B-chunks per tile
      int row = c >> 3, cc = c & 7;
      int scc = cc ^ (row & 7);    // pre-swizzled SOURCE granule (read side keeps same XOR)
      int ar = bm + row; if (ar > M - 1) ar = M - 1;
      gload_lds16(A + (size_t)ar * K + kb + scc * 8, &As[(size_t)(w * 64 + 256 * i) * 8]);
      gload_lds16(B + (size_t)(bn + row) * K + kb + scc * 8,
                  &Bs[(size_t)(w * 64 + 256 * i) * 8]);
    }
    __syncthreads();
#pragma unroll
    for (int kk = 0; kk < 2; ++kk) {
      bf16x8 af[4], bfr[4];
#pragma unroll
      for (int m = 0; m < 4; ++m) {
        int row = wr * 64 + m * 16 + (l & 15);
        int g = (kk * 4 + (l >> 4)) ^ (row & 7);
        af[m] = *(const bf16x8*)&As[row * 64 + g * 8];
      }
#pragma unroll
      for (int n = 0; n < 4; ++n) {
        int row = wc * 64 + n * 16 + (l & 15);
        int g = (kk * 4 + (l >> 4)) ^ (row & 7);
        bfr[n] = *(const bf16x8*)&Bs[row * 64 + g * 8];
      }
#pragma unroll
      for (int m = 0; m < 4; ++m)
#pragma unroll
        for (int n = 0; n < 4; ++n)
          acc[m][n] = __builtin_amdgcn_mfma_f32_16x16x32_bf16(af[m], bfr[n], acc[m][n], 0, 0, 0);
    }
  }
#pragma unroll
  for (int m = 0; m < 4; ++m) {
    int r0 = bm + wr * 64 + m * 16 + ((l >> 4) << 2);
#pragma unroll
    for (int n = 0; n < 4; ++n) {
      int c0 = bn + wc * 64 + n * 16 + (l & 15);
#pragma unroll
      for (int r = 0; r < 4; ++r) {
        int row = r0 + r;
        if (row < M) C[(size_t)row * Nc + c0] = f2bf(acc[m][n][r]);
      }
    }
  }
}

// ---------------- el/er: per (node, head) dot(feat, al/ar) ----------------
__global__ void k_el_er(const unsigned short* __restrict__ feat, int fstride,
                        const float* __restrict__ al, const float* __restrict__ ar,
                        float* __restrict__ el, float* __restrict__ er) {
  int wid = (blockIdx.x * blockDim.x + threadIdx.x) >> 6;
  if (wid >= N_NODES) return;
  int l = threadIdx.x & 63;
  int g = l >> 4, q = l & 15;
  u16x8 fv = *(const u16x8*)(feat + (size_t)wid * fstride + l * 8);
  const float* alp = al + g * 128 + q * 8;
  const float* arp = ar + g * 128 + q * 8;
  float sl = 0.f, sr = 0.f;
#pragma unroll
  for (int j = 0; j < 8; ++j) { float f = bf2f(fv[j]); sl += f * alp[j]; sr += f * arp[j]; }
#pragma unroll
  for (int d = 1; d < 16; d <<= 1) { sl += __shfl_xor(sl, d); sr += __shfl_xor(sr, d); }
  if (q == 0) { el[wid * 4 + g] = sl; er[wid * 4 + g] = sr; }
}

// ---------------- CSR build ----------------
__global__ void k_hist(const int* __restrict__ dst, int* __restrict__ indeg) {
  int e = blockIdx.x * blockDim.x + threadIdx.x;
  if (e < N_EDGES) atomicAdd(&indeg[dst[e]], 1);
}

__global__ __launch_bounds__(1024) void k_scan_fast(const int* __restrict__ indeg,
                                                    int* __restrict__ indptr,
                                                    int* __restrict__ cursor) {
  __shared__ int wsum[16];
  const int t = threadIdx.x;
  const int l = t & 63, w = t >> 6;
  const int CH = 20;  // 1024*20 >= 20000
  int base = t * CH;
  int vals[CH];
  int s = 0;
#pragma unroll
  for (int i = 0; i < CH; ++i) {
    int idx = base + i;
    int v = (idx < N_NODES) ? indeg[idx] : 0;
    vals[i] = v;
    s += v;
  }
  int ss = s;
#pragma unroll
  for (int d = 1; d < 64; d <<= 1) { int o = __shfl_up(ss, d); if (l >= d) ss += o; }
  if (l == 63) wsum[w] = ss;
  __syncthreads();
  if (t < 16) {
    int v = wsum[t];
#pragma unroll
    for (int d = 1; d < 16; d <<= 1) { int o = __shfl_up(v, d); if (t >= d) v += o; }
    wsum[t] = v;
  }
  __syncthreads();
  int run = ((w > 0) ? wsum[w - 1] : 0) + ss - s;
  if (t == 0) indptr[0] = 0;
#pragma unroll
  for (int i = 0; i < CH; ++i) {
    int idx = base + i;
    if (idx < N_NODES) {
      cursor[idx] = run;
      run += vals[i];
      indptr[idx + 1] = run;
    }
  }
}

__global__ void k_scatter(const int* __restrict__ src, const int* __restrict__ dst,
                          int* __restrict__ cursor, int* __restrict__ csr_src) {
  int e = blockIdx.x * blockDim.x + threadIdx.x;
  if (e < N_EDGES) {
    int p = atomicAdd(&cursor[dst[e]], 1);
    csr_src[p] = src[e];
  }
}

// ---------------- GAT edge-softmax + aggregation (wave per dst node) ----------------
// no-max softmax (alpha invariant to shift; |e| << 88 so exp is safe),
// 4-deep unrolled gather loop
template <bool FINAL>
__global__ void k_gat_agg(const unsigned short* __restrict__ feat,
                          const unsigned short* __restrict__ hres, int fstride,
                          const float* __restrict__ el, const float* __restrict__ er,
                          const int* __restrict__ indptr, const int* __restrict__ csr_src,
                          unsigned short* __restrict__ hnext, float* __restrict__ h3,
                          unsigned short* __restrict__ h3b) {
  int wid = (blockIdx.x * blockDim.x + threadIdx.x) >> 6;
  if (wid >= N_NODES) return;
  int l = threadIdx.x & 63;
  int g = l >> 4;
  int beg = indptr[wid], end = indptr[wid + 1];
  float er_g = er[wid * 4 + g];
  float asum = 0.f;
  float acc[8];
#pragma unroll
  for (int j2 = 0; j2 < 8; ++j2) acc[j2] = 0.f;
  const unsigned short* fbase = feat + l * 8;
  int j = beg;
  for (; j + 4 <= end; j += 4) {
    int s0 = csr_src[j + 0], s1 = csr_src[j + 1];
    int s2 = csr_src[j + 2], s3 = csr_src[j + 3];
    float q0 = el[s0 * 4 + g], q1 = el[s1 * 4 + g];
    float q2 = el[s2 * 4 + g], q3 = el[s3 * 4 + g];
    u16x8 f0 = *(const u16x8*)(fbase + (size_t)s0 * fstride);
    u16x8 f1 = *(const u16x8*)(fbase + (size_t)s1 * fstride);
    u16x8 f2 = *(const u16x8*)(fbase + (size_t)s2 * fstride);
    u16x8 f3 = *(const u16x8*)(fbase + (size_t)s3 * fstride);
    float e0 = q0 + er_g; e0 = (e0 >= 0.f) ? e0 : 0.2f * e0;
    float e1 = q1 + er_g; e1 = (e1 >= 0.f) ? e1 : 0.2f * e1;
    float e2 = q2 + er_g; e2 = (e2 >= 0.f) ? e2 : 0.2f * e2;
    float e3 = q3 + er_g; e3 = (e3 >= 0.f) ? e3 : 0.2f * e3;
    float p0 = __expf(e0), p1 = __expf(e1);
    float p2 = __expf(e2), p3 = __expf(e3);
    asum += (p0 + p1) + (p2 + p3);
#pragma unroll
    for (int k = 0; k < 8; ++k)
      acc[k] += p0 * bf2f(f0[k]) + p1 * bf2f(f1[k]) + p2 * bf2f(f2[k]) + p3 * bf2f(f3[k]);
  }
  for (; j < end; ++j) {
    int s = csr_src[j];
    float ev = el[s * 4 + g] + er_g;
    ev = (ev >= 0.f) ? ev : 0.2f * ev;
    float p = __expf(ev);
    asum += p;
    u16x8 fv = *(const u16x8*)(fbase + (size_t)s * fstride);
#pragma unroll
    for (int k = 0; k < 8; ++k) acc[k] += p * bf2f(fv[k]);
  }
  float inv = (end > beg) ? 1.f / asum : 1.f;
  u16x8 hv = *(const u16x8*)(hres + (size_t)wid * fstride + l * 8);
  float o[8];
#pragma unroll
  for (int k = 0; k < 8; ++k) o[k] = acc[k] * inv + bf2f(hv[k]);
  if constexpr (!FINAL) {
    u16x8 ob;
#pragma unroll
    for (int k = 0; k < 8; ++k) ob[k] = f2bf(fmaxf(o[k], 0.f));
    *(u16x8*)(hnext + (size_t)wid * 512 + l * 8) = ob;
  } else {
#pragma unroll
    for (int k = 0; k < 8; ++k) {
      float v = o[k];
      v += __shfl_xor(v, 16);
      v += __shfl_xor(v, 32);
      o[k] = v * 0.25f;
    }
    if (g == 0) {
      f32x4 o0 = (f32x4){o[0], o[1], o[2], o[3]};
      f32x4 o1 = (f32x4){o[4], o[5], o[6], o[7]};
      *(f32x4*)(h3 + (size_t)wid * 128 + l * 8) = o0;
      *(f32x4*)(h3 + (size_t)wid * 128 + l * 8 + 4) = o1;
      u16x8 hb;
#pragma unroll
      for (int k = 0; k < 8; ++k) hb[k] = f2bf(o[k]);
      *(u16x8*)(h3b + (size_t)wid * 128 + l * 8) = hb;
    }
  }
}

// ---- fused pair MLP v4: direct-to-register X gather + W in LDS (pre-swizzled) ----
template <int MODE>
__global__ __launch_bounds__(256) void k_pair_mlp(
    const unsigned short* __restrict__ X, const int* __restrict__ ia,
    const int* __restrict__ ib, const unsigned short* __restrict__ WbSwz,
    const float* __restrict__ b1, const float* __restrict__ W2,
    const float* __restrict__ b2, float* __restrict__ out, int npairs) {
  __shared__ __align__(16) unsigned short Ws[128 * 128];  // 32 KB
  const int t = threadIdx.x;
  const int l = t & 63, w = t >> 6;
#pragma unroll
  for (int i = 0; i < 8; ++i)
    gload_lds16(WbSwz + i * 2048 + w * 512 + l * 8, &Ws[i * 2048 + w * 512]);
  const int base = blockIdx.x * 128 + w * 32;
  bf16x8 af[2][4];
#pragma unroll
  for (int m = 0; m < 2; ++m) {
    int e = base + m * 16 + (l & 15);
    if (MODE == 1 && e >= npairs) e = npairs - 1;
    int sa, sb;
    if (MODE == 0) { sa = ia[e]; sb = ib[e]; }
    else           { sa = ia[e]; sb = e / KNN_K; }
    const unsigned short* pa = X + (size_t)sa * 128 + (l >> 4) * 8;
    const unsigned short* pb = X + (size_t)sb * 128 + (l >> 4) * 8;
#pragma unroll
    for (int kk = 0; kk < 4; ++kk) {
      u16x8 av = *(const u16x8*)(pa + kk * 32);
      u16x8 bv = *(const u16x8*)(pb + kk * 32);
      u16x8 xv;
#pragma unroll
      for (int j = 0; j < 8; ++j) xv[j] = f2bf(fabsf(bf2f(av[j]) - bf2f(bv[j])));
      af[m][kk] = *(bf16x8*)&xv;
    }
  }
  __syncthreads();  // W staged (drains vmcnt)
  float part[2][4];
#pragma unroll
  for (int m = 0; m < 2; ++m)
#pragma unroll
    for (int r = 0; r < 4; ++r) part[m][r] = 0.f;
#pragma unroll
  for (int n = 0; n < 8; ++n) {
    int rowv = n * 16 + (l & 15);
    bf16x8 bfr[4];
#pragma unroll
    for (int kk = 0; kk < 4; ++kk) {
      int sg = (kk * 4 + (l >> 4)) ^ (rowv & 15);
      bfr[kk] = *(const bf16x8*)&Ws[rowv * 128 + sg * 8];
    }
    f32x4 acc0 = (f32x4){0.f, 0.f, 0.f, 0.f};
    f32x4 acc1 = (f32x4){0.f, 0.f, 0.f, 0.f};
#pragma unroll
    for (int kk = 0; kk < 4; ++kk) {
      acc0 = __builtin_amdgcn_mfma_f32_16x16x32_bf16(af[0][kk], bfr[kk], acc0, 0, 0, 0);
      acc1 = __builtin_amdgcn_mfma_f32_16x16x32_bf16(af[1][kk], bfr[kk], acc1, 0, 0, 0);
    }
    float bb = b1[rowv], w2v = W2[rowv];
#pragma unroll
    for (int r = 0; r < 4; ++r) {
      part[0][r] += fmaxf(acc0[r] + bb, 0.f) * w2v;
      part[1][r] += fmaxf(acc1[r] + bb, 0.f) * w2v;
    }
  }
#pragma unroll
  for (int d = 1; d < 16; d <<= 1)
#pragma unroll
    for (int m = 0; m < 2; ++m)
#pragma unroll
      for (int r = 0; r < 4; ++r) part[m][r] += __shfl_xor(part[m][r], d);
  if ((l & 15) == 0) {
    int q = l >> 4;
    float b2v = b2[0];
#pragma unroll
    for (int m = 0; m < 2; ++m) {
      int e = base + m * 16 + q * 4;
      f32x4 ov;
#pragma unroll
      for (int r = 0; r < 4; ++r) ov[r] = sigmoidf(part[m][r] + b2v);
      if (e + 3 < npairs) *(f32x4*)(out + e) = ov;
      else {
#pragma unroll
        for (int r = 0; r < 4; ++r) if (e + r < npairs) out[e + r] = ov[r];
      }
    }
  }
}

// ---------------- entity segment sums ----------------
__global__ void k_ent_scatter(const float* __restrict__ h3, const float* __restrict__ pos,
                              const int* __restrict__ entity, float* __restrict__ ent_sum,
                              float* __restrict__ pos_sum, float* __restrict__ cnt) {
  int i = blockIdx.x * blockDim.x + threadIdx.x;
  if (i >= N_NODES * 32) return;
  int n = i >> 5, c = i & 31;
  int e = entity[n];
  f32x4 v = *(const f32x4*)(h3 + (size_t)n * 128 + c * 4);
  atomicAdd(&ent_sum[e * 128 + c * 4 + 0], v[0]);
  atomicAdd(&ent_sum[e * 128 + c * 4 + 1], v[1]);
  atomicAdd(&ent_sum[e * 128 + c * 4 + 2], v[2]);
  atomicAdd(&ent_sum[e * 128 + c * 4 + 3], v[3]);
  if (c == 0) {
    atomicAdd(&pos_sum[e * 2 + 0], pos[n * 2 + 0]);
    atomicAdd(&pos_sum[e * 2 + 1], pos[n * 2 + 1]);
    atomicAdd(&cnt[e], 1.f);
  }
}

__global__ void k_entity_states(const float* __restrict__ ent_sum, const float* __restrict__ We,
                                const float* __restrict__ be, float* __restrict__ es) {
  int i = blockIdx.x * blockDim.x + threadIdx.x;
  if (i >= NENT * 128) return;
  int e = i >> 7, j = i & 127;
  const float* x = ent_sum + (size_t)e * 128;
  const float* wrow = We + (size_t)j * 128;
  float s = be[j];
  for (int k = 0; k < 128; k += 4) {
    f32x4 xv = *(const f32x4*)(x + k);
    f32x4 wv = *(const f32x4*)(wrow + k);
    s += xv[0] * wv[0] + xv[1] * wv[1] + xv[2] * wv[2] + xv[3] * wv[3];
  }
  es[i] = s;
}

__global__ void k_entity_class(const float* __restrict__ es, const float* __restrict__ Wc,
                               const float* __restrict__ bc, float* __restrict__ out) {
  int i = blockIdx.x * blockDim.x + threadIdx.x;
  if (i >= NENT * 4) return;
  int e = i >> 2, c = i & 3;
  const float* x = es + (size_t)e * 128;
  const float* wrow = Wc + (size_t)c * 128;
  float s = bc[c];
  for (int k = 0; k < 128; ++k) s += x[k] * wrow[k];
  out[i] = sigmoidf(s);
}

__global__ void k_entity_pos(const float* __restrict__ pos_sum, const float* __restrict__ cnt,
                             float* __restrict__ outpos, float* __restrict__ wspos) {
  int e = blockIdx.x * blockDim.x + threadIdx.x;
  if (e >= NENT) return;
  float c = fmaxf(cnt[e], 1.f);
  float x = pos_sum[e * 2] / c, y = pos_sum[e * 2 + 1] / c;
  outpos[e * 2] = x; outpos[e * 2 + 1] = y;
  wspos[e * 2] = x; wspos[e * 2 + 1] = y;
}

// ---------------- exact knn (K smallest d2, ties -> smaller index) ----------------
__global__ __launch_bounds__(256) void k_knn(const float* __restrict__ entpos,
                                             int* __restrict__ knn) {
  __shared__ float d2row[NENT];
  __shared__ float rv[256];
  __shared__ int ri[256];
  int i = blockIdx.x, t = threadIdx.x;
  float px = entpos[i * 2], py = entpos[i * 2 + 1];
  for (int j = t; j < NENT; j += 256) {
    float dx = px - entpos[j * 2], dy = py - entpos[j * 2 + 1];
    d2row[j] = __fadd_rn(__fmul_rn(dx, dx), __fmul_rn(dy, dy));
  }
  __syncthreads();
  for (int k = 0; k < KNN_K; ++k) {
    float bv = __builtin_inff(); int bi = 0x7fffffff;
    for (int j = t; j < NENT; j += 256) {
      float v = d2row[j];
      if (v < bv) { bv = v; bi = j; }
    }
    rv[t] = bv; ri[t] = bi;
    __syncthreads();
    for (int s = 128; s > 0; s >>= 1) {
      if (t < s) {
        if (rv[t + s] < rv[t] || (rv[t + s] == rv[t] && ri[t + s] < ri[t])) {
          rv[t] = rv[t + s]; ri[t] = ri[t + s];
        }
      }
      __syncthreads();
    }
    if (t == 0) { knn[i * KNN_K + k] = ri[0]; d2row[ri[0]] = __builtin_inff(); }
    __syncthreads();
  }
}

// =======================================================================
extern "C" void kernel_launch(void* const* d_in, const int* in_sizes, int n_in,
                              void* d_out, int out_size, void* d_ws, size_t ws_size,
                              hipStream_t stream) {
  const float* position = (const float*)d_in[0];
  const float* w_embed  = (const float*)d_in[1];
  const int*   src      = (const int*)d_in[2];
  const int*   dst      = (const int*)d_in[3];
  const int*   entity   = (const int*)d_in[4];
  const float* W1 = (const float*)d_in[5];
  const float* al1 = (const float*)d_in[6];
  const float* ar1 = (const float*)d_in[7];
  const float* Wr1 = (const float*)d_in[8];
  const float* W2 = (const float*)d_in[9];
  const float* al2 = (const float*)d_in[10];
  const float* ar2 = (const float*)d_in[11];
  const float* Wr2 = (const float*)d_in[12];
  const float* W3 = (const float*)d_in[13];
  const float* al3 = (const float*)d_in[14];
  const float* ar3 = (const float*)d_in[15];
  const float* Wr3 = (const float*)d_in[16];
  const float* Wg1 = (const float*)d_in[17];
  const float* bg1 = (const float*)d_in[18];
  const float* Wg2 = (const float*)d_in[19];
  const float* bg2 = (const float*)d_in[20];
  const float* We  = (const float*)d_in[21];
  const float* be  = (const float*)d_in[22];
  const float* Wl1 = (const float*)d_in[23];
  const float* bl1 = (const float*)d_in[24];
  const float* Wl2 = (const float*)d_in[25];
  const float* bl2 = (const float*)d_in[26];
  const float* Wc  = (const float*)d_in[27];
  const float* bc  = (const float*)d_in[28];

  float* out_groups = (float*)d_out;
  float* out_class  = out_groups + N_EDGES;
  float* out_pos    = out_class + NENT * 4;
  float* out_link   = out_pos + NENT * 2;

  char* ws = (char*)d_ws;
  size_t off = 0;
  auto carve = [&](size_t bytes) -> char* {
    char* p = ws + off;
    off = (off + bytes + 255) & ~(size_t)255;
    return p;
  };
  // fused GEMM output: [N, 1024] bf16 — cols 0..511 = feat, 512..1023 = hres
  unsigned short* featC = (unsigned short*)carve((size_t)N_NODES * 1024 * 2);
  unsigned short* hA = (unsigned short*)carve((size_t)N_NODES * 512 * 2);
  unsigned short* hB = (unsigned short*)carve((size_t)N_NODES * 512 * 2);
  unsigned short* wbf1 = (unsigned short*)carve((size_t)1024 * 128 * 2);  // [W1;Wr1]
  unsigned short* wbf2 = (unsigned short*)carve((size_t)1024 * 512 * 2);  // [W2;Wr2]
  unsigned short* wbf3 = (unsigned short*)carve((size_t)1024 * 512 * 2);  // [W3;Wr3]
  unsigned short* wg1b = (unsigned short*)carve(128 * 128 * 2);
  unsigned short* wl1b = (unsigned short*)carve(128 * 128 * 2);
  float* el = (float*)carve((size_t)N_NODES * 4 * 4);
  float* er = (float*)carve((size_t)N_NODES * 4 * 4);
  int* indeg = (int*)carve((size_t)N_NODES * 4);
  int* indptr = (int*)carve((size_t)(N_NODES + 1) * 4);
  int* cursor = (int*)carve((size_t)N_NODES * 4);
  int* csr_src = (int*)carve((size_t)N_EDGES * 4);
  float* h3 = (float*)carve((size_t)N_NODES * 128 * 4);
  unsigned short* h3b = (unsigned short*)carve((size_t)N_NODES * 128 * 2);
  float* ent_sum = (float*)carve((size_t)NENT * 128 * 4);
  float* pos_sum = (float*)carve((size_t)NENT * 2 * 4);
  float* cnt = (float*)carve((size_t)NENT * 4);
  float* es = (float*)carve((size_t)NENT * 128 * 4);
  unsigned short* esb = (unsigned short*)carve((size_t)NENT * 128 * 2);
  float* wspos = (float*)carve((size_t)NENT * 2 * 4);
  int* knn = (int*)carve((size_t)NENT * KNN_K * 4);

  // ---- CSR over dst (shared by all 3 GAT layers) ----
  hipMemsetAsync(indeg, 0, (size_t)N_NODES * 4, stream);
  k_hist<<<(N_EDGES + 255) / 256, 256, 0, stream>>>(dst, indeg);
  k_scan_fast<<<1, 1024, 0, stream>>>(indeg, indptr, cursor);
  k_scatter<<<(N_EDGES + 255) / 256, 256, 0, stream>>>(src, dst, cursor, csr_src);

  k_build_h0<<<(N_NODES * 128 + 255) / 256, 256, 0, stream>>>(position, w_embed, hA);

  // ---- all weight conversions in one launch ----
  k_conv_weights<<<(303104 + 255) / 256, 256, 0, stream>>>(W1, Wr1, W2, Wr2, W3, Wr3, Wg1, Wl1,
                                                           wbf1, wbf2, wbf3, wg1b, wl1b);

  // XCD-grouped 1D grid: 160 bm-slots (157 used) x 8 bn
  const int NBM = (N_NODES + 127) / 128;  // 157
  const int GGRID = 160 * 8;

  // ---- layer 1 (K=128), fused W|Wr GEMM ----
  k_gemm_bt<<<GGRID, 256, 0, stream>>>(hA, wbf1, featC, N_NODES, 1024, 128, NBM);
  k_el_er<<<5000, 256, 0, stream>>>(featC, 1024, al1, ar1, el, er);
  k_gat_agg<false><<<5000, 256, 0, stream>>>(featC, featC + 512, 1024, el, er, indptr,
                                             csr_src, hB, nullptr, nullptr);

  // ---- layer 2 (K=512) ----
  k_gemm_bt<<<GGRID, 256, 0, stream>>>(hB, wbf2, featC, N_NODES, 1024, 512, NBM);
  k_el_er<<<5000, 256, 0, stream>>>(featC, 1024, al2, ar2, el, er);
  k_gat_agg<false><<<5000, 256, 0, stream>>>(featC, featC + 512, 1024, el, er, indptr,
                                             csr_src, hA, nullptr, nullptr);

  // ---- layer 3 (K=512, no relu, head-mean) ----
  k_gemm_bt<<<GGRID, 256, 0, stream>>>(hA, wbf3, featC, N_NODES, 1024, 512, NBM);
  k_el_er<<<5000, 256, 0, stream>>>(featC, 1024, al3, ar3, el, er);
  k_gat_agg<true><<<5000, 256, 0, stream>>>(featC, featC + 512, 1024, el, er, indptr,
                                            csr_src, nullptr, h3, h3b);

  // ---- groups_score (pair MLP v4 on bf16 h3) ----
  k_pair_mlp<0><<<N_EDGES / 128, 256, 0, stream>>>(h3b, src, dst, wg1b, bg1, Wg2, bg2,
                                                   out_groups, N_EDGES);

  // ---- entity path (ent_sum/pos_sum/cnt contiguous -> one memset) ----
  size_t zbytes = (size_t)((char*)cnt - (char*)ent_sum) + NENT * 4;
  hipMemsetAsync(ent_sum, 0, zbytes, stream);
  k_ent_scatter<<<(N_NODES * 32 + 255) / 256, 256, 0, stream>>>(h3, position, entity, ent_sum,
                                                                pos_sum, cnt);
  k_entity_states<<<(NENT * 128 + 255) / 256, 256, 0, stream>>>(ent_sum, We, be, es);
  k_entity_class<<<(NENT * 4 + 255) / 256, 256, 0, stream>>>(es, Wc, bc, out_class);
  k_entity_pos<<<(NENT + 255) / 256, 256, 0, stream>>>(pos_sum, cnt, out_pos, wspos);
  k_knn<<<NENT, 256, 0, stream>>>(wspos, knn);
  k_f2bf<<<(NENT * 128 / 4 + 255) / 256, 256, 0, stream>>>(es, esb, NENT * 128);
  k_pair_mlp<1><<<(NENT * KNN_K + 127) / 128, 256, 0, stream>>>(esb, knn, nullptr, wl1b, bl1,
                                                                Wl2, bl2, out_link,
                                                                NENT * KNN_K);
}

// Round 13
// 425.367 us; speedup vs baseline: 1.1617x; 1.0368x over previous
//
#include <hip/hip_runtime.h>
#include <math.h>

#define N_NODES 20000
#define N_EDGES 320000
#define NENT    2000
#define KNN_K   10

typedef __attribute__((ext_vector_type(4))) float f32x4;
typedef __attribute__((ext_vector_type(8))) short bf16x8;
typedef __attribute__((ext_vector_type(8))) unsigned short u16x8;
typedef __attribute__((ext_vector_type(4))) unsigned short u16x4;

__device__ __forceinline__ unsigned short f2bf(float f) {
  union { float f; unsigned u; } v; v.f = f;
  unsigned r = v.u + 0x7fffu + ((v.u >> 16) & 1u);
  return (unsigned short)(r >> 16);
}
__device__ __forceinline__ float bf2f(unsigned short u) {
  union { unsigned u; float f; } v; v.u = ((unsigned)u) << 16;
  return v.f;
}
__device__ __forceinline__ float sigmoidf(float x) {
  return 1.f / (1.f + __expf(-x));
}
// async global->LDS, 16B per lane; lds dest = wave-uniform base + lane*16
__device__ __forceinline__ void gload_lds16(const unsigned short* g, unsigned short* lds) {
  __builtin_amdgcn_global_load_lds(
      (const __attribute__((address_space(1))) unsigned int*)g,
      (__attribute__((address_space(3))) unsigned int*)lds, 16, 0, 0);
}

// ---- h0 build + ALL weight conversions in ONE launch ----
__global__ void k_init(
    const float* __restrict__ pos, const float* __restrict__ wemb,
    const float* __restrict__ W1, const float* __restrict__ Wr1,
    const float* __restrict__ W2, const float* __restrict__ Wr2,
    const float* __restrict__ W3, const float* __restrict__ Wr3,
    const float* __restrict__ Wg1, const float* __restrict__ Wl1,
    unsigned short* __restrict__ h0,
    unsigned short* __restrict__ wbf1, unsigned short* __restrict__ wbf2,
    unsigned short* __restrict__ wbf3, unsigned short* __restrict__ wg1b,
    unsigned short* __restrict__ wl1b) {
  int tid = blockIdx.x * blockDim.x + threadIdx.x;
  if (tid < 640000) {  // h0: N_NODES*128 elements, 4 per thread
    int i = tid * 4;
    int n = i >> 7, c = i & 127;
    u16x4 o;
    if (c == 0) {
      o[0] = f2bf(pos[n * 2]); o[1] = f2bf(pos[n * 2 + 1]);
      o[2] = f2bf(wemb[n * 126]); o[3] = f2bf(wemb[n * 126 + 1]);
    } else {
      const float* p = wemb + (size_t)n * 126 + (c - 2);
      o[0] = f2bf(p[0]); o[1] = f2bf(p[1]); o[2] = f2bf(p[2]); o[3] = f2bf(p[3]);
    }
    *(u16x4*)(h0 + i) = o;
    return;
  }
  int i4 = (tid - 640000) * 4;
  const float* src;
  unsigned short* dst;
  if (i4 < 131072) {
    src = (i4 < 65536) ? (W1 + i4) : (Wr1 + i4 - 65536);
    dst = wbf1 + i4;
  } else if ((i4 -= 131072) < 524288) {
    src = (i4 < 262144) ? (W2 + i4) : (Wr2 + i4 - 262144);
    dst = wbf2 + i4;
  } else if ((i4 -= 524288) < 524288) {
    src = (i4 < 262144) ? (W3 + i4) : (Wr3 + i4 - 262144);
    dst = wbf3 + i4;
  } else if ((i4 -= 524288) < 32768) {
    // swizzled 128x128: 4 consecutive k stay contiguous after swizzle
    const float* W = (i4 < 16384) ? Wg1 : Wl1;
    unsigned short* O = (i4 < 16384) ? wg1b : wl1b;
    int ii = i4 & 16383;
    int row = ii >> 7, k = ii & 127;
    int sg = (k >> 3) ^ (row & 15);
    src = W + ii;
    dst = O + row * 128 + sg * 8 + (k & 7);
  } else {
    return;
  }
  f32x4 v = *(const f32x4*)src;
  u16x4 o;
  o[0] = f2bf(v[0]); o[1] = f2bf(v[1]); o[2] = f2bf(v[2]); o[3] = f2bf(v[3]);
  *(u16x4*)dst = o;
}

// ------- bf16 MFMA GEMM: C[M,Nc] = A[M,K] * B[Nc,K]^T, bf16 out, stride Nc -------
// 1D grid, XCD-grouped decomposition: the 8 bn-blocks of one bm share id%8
// (one XCD) so the A-panel is fetched once per XCD instead of 8x.
__global__ __launch_bounds__(256) void k_gemm_bt(
    const unsigned short* __restrict__ A, const unsigned short* __restrict__ B,
    unsigned short* __restrict__ C, int M, int Nc, int K, int nbm) {
  const int id = blockIdx.x;
  const int bm128 = (id & 7) + 8 * (id >> 6);
  const int bn128 = (id >> 3) & 7;
  if (bm128 >= nbm) return;  // uniform exit before any barrier
  __shared__ __align__(16) unsigned short As[128 * 64];
  __shared__ __align__(16) unsigned short Bs[128 * 64];
  const int bm = bm128 * 128, bn = bn128 * 128;
  const int t = threadIdx.x;
  const int l = t & 63, w = t >> 6;
  const int wr = w >> 1, wc = w & 1;
  f32x4 acc[4][4];
#pragma unroll
  for (int m = 0; m < 4; ++m)
#pragma unroll
    for (int n = 0; n < 4; ++n) acc[m][n] = (f32x4){0.f, 0.f, 0.f, 0.f};

  for (int kb = 0; kb < K; kb += 64) {
    __syncthreads();
#pragma unroll
    for (int i = 0; i < 4; ++i) {
      int c = t + 256 * i;         // 1024 16B-chunks per tile
      int row = c >> 3, cc = c & 7;
      int scc = cc ^ (row & 7);    // pre-swizzled SOURCE granule (read side keeps same XOR)
      int ar = bm + row; if (ar > M - 1) ar = M - 1;
      gload_lds16(A + (size_t)ar * K + kb + scc * 8, &As[(size_t)(w * 64 + 256 * i) * 8]);
      gload_lds16(B + (size_t)(bn + row) * K + kb + scc * 8,
                  &Bs[(size_t)(w * 64 + 256 * i) * 8]);
    }
    __syncthreads();
#pragma unroll
    for (int kk = 0; kk < 2; ++kk) {
      bf16x8 af[4], bfr[4];
#pragma unroll
      for (int m = 0; m < 4; ++m) {
        int row = wr * 64 + m * 16 + (l & 15);
        int g = (kk * 4 + (l >> 4)) ^ (row & 7);
        af[m] = *(const bf16x8*)&As[row * 64 + g * 8];
      }
#pragma unroll
      for (int n = 0; n < 4; ++n) {
        int row = wc * 64 + n * 16 + (l & 15);
        int g = (kk * 4 + (l >> 4)) ^ (row & 7);
        bfr[n] = *(const bf16x8*)&Bs[row * 64 + g * 8];
      }
#pragma unroll
      for (int m = 0; m < 4; ++m)
#pragma unroll
        for (int n = 0; n < 4; ++n)
          acc[m][n] = __builtin_amdgcn_mfma_f32_16x16x32_bf16(af[m], bfr[n], acc[m][n], 0, 0, 0);
    }
  }
#pragma unroll
  for (int m = 0; m < 4; ++m) {
    int r0 = bm + wr * 64 + m * 16 + ((l >> 4) << 2);
#pragma unroll
    for (int n = 0; n < 4; ++n) {
      int c0 = bn + wc * 64 + n * 16 + (l & 15);
#pragma unroll
      for (int r = 0; r < 4; ++r) {
        int row = r0 + r;
        if (row < M) C[(size_t)row * Nc + c0] = f2bf(acc[m][n][r]);
      }
    }
  }
}

// ---------------- el/er: per (node, head) dot(feat, al/ar) ----------------
__global__ void k_el_er(const unsigned short* __restrict__ feat, int fstride,
                        const float* __restrict__ al, const float* __restrict__ ar,
                        float* __restrict__ el, float* __restrict__ er) {
  int wid = (blockIdx.x * blockDim.x + threadIdx.x) >> 6;
  if (wid >= N_NODES) return;
  int l = threadIdx.x & 63;
  int g = l >> 4, q = l & 15;
  u16x8 fv = *(const u16x8*)(feat + (size_t)wid * fstride + l * 8);
  const float* alp = al + g * 128 + q * 8;
  const float* arp = ar + g * 128 + q * 8;
  float sl = 0.f, sr = 0.f;
#pragma unroll
  for (int j = 0; j < 8; ++j) { float f = bf2f(fv[j]); sl += f * alp[j]; sr += f * arp[j]; }
#pragma unroll
  for (int d = 1; d < 16; d <<= 1) { sl += __shfl_xor(sl, d); sr += __shfl_xor(sr, d); }
  if (q == 0) { el[wid * 4 + g] = sl; er[wid * 4 + g] = sr; }
}

// ---------------- CSR build ----------------
__global__ void k_hist(const int* __restrict__ dst, int* __restrict__ indeg) {
  int e = blockIdx.x * blockDim.x + threadIdx.x;
  if (e < N_EDGES) atomicAdd(&indeg[dst[e]], 1);
}

__global__ __launch_bounds__(1024) void k_scan_fast(const int* __restrict__ indeg,
                                                    int* __restrict__ indptr,
                                                    int* __restrict__ cursor) {
  __shared__ int wsum[16];
  const int t = threadIdx.x;
  const int l = t & 63, w = t >> 6;
  const int CH = 20;  // 1024*20 >= 20000
  int base = t * CH;
  int vals[CH];
  int s = 0;
#pragma unroll
  for (int i = 0; i < CH; ++i) {
    int idx = base + i;
    int v = (idx < N_NODES) ? indeg[idx] : 0;
    vals[i] = v;
    s += v;
  }
  int ss = s;
#pragma unroll
  for (int d = 1; d < 64; d <<= 1) { int o = __shfl_up(ss, d); if (l >= d) ss += o; }
  if (l == 63) wsum[w] = ss;
  __syncthreads();
  if (t < 16) {
    int v = wsum[t];
#pragma unroll
    for (int d = 1; d < 16; d <<= 1) { int o = __shfl_up(v, d); if (t >= d) v += o; }
    wsum[t] = v;
  }
  __syncthreads();
  int run = ((w > 0) ? wsum[w - 1] : 0) + ss - s;
  if (t == 0) indptr[0] = 0;
#pragma unroll
  for (int i = 0; i < CH; ++i) {
    int idx = base + i;
    if (idx < N_NODES) {
      cursor[idx] = run;
      run += vals[i];
      indptr[idx + 1] = run;
    }
  }
}

__global__ void k_scatter(const int* __restrict__ src, const int* __restrict__ dst,
                          int* __restrict__ cursor, int* __restrict__ csr_src) {
  int e = blockIdx.x * blockDim.x + threadIdx.x;
  if (e < N_EDGES) {
    int p = atomicAdd(&cursor[dst[e]], 1);
    csr_src[p] = src[e];
  }
}

// ---------------- GAT edge-softmax + aggregation ----------------
// 2 waves per node (edge-split halves), LDS combine; no-max softmax;
// 4-deep unrolled gather loop per wave. Grid = N_NODES/2 blocks x 256.
template <bool FINAL>
__global__ __launch_bounds__(256) void k_gat_agg(
    const unsigned short* __restrict__ feat, const unsigned short* __restrict__ hres,
    int fstride, const float* __restrict__ el, const float* __restrict__ er,
    const int* __restrict__ indptr, const int* __restrict__ csr_src,
    unsigned short* __restrict__ hnext, float* __restrict__ h3,
    unsigned short* __restrict__ h3b) {
  __shared__ float lacc[2][512];
  __shared__ float lsum[2][4];
  const int t = threadIdx.x;
  const int l = t & 63, w = t >> 6;
  const int nib = w >> 1, sub = w & 1;
  const int wid = blockIdx.x * 2 + nib;   // grid sized exactly: always < N_NODES
  const int g = l >> 4;
  int beg = indptr[wid], end = indptr[wid + 1];
  int cnt = end - beg;
  int half = (cnt + 1) >> 1;
  int jb = beg + sub * half;
  int je = sub ? end : (beg + half);
  float er_g = er[wid * 4 + g];
  float asum = 0.f;
  float acc[8];
#pragma unroll
  for (int k = 0; k < 8; ++k) acc[k] = 0.f;
  const unsigned short* fbase = feat + l * 8;
  int j = jb;
  for (; j + 4 <= je; j += 4) {
    int s0 = csr_src[j + 0], s1 = csr_src[j + 1];
    int s2 = csr_src[j + 2], s3 = csr_src[j + 3];
    float q0 = el[s0 * 4 + g], q1 = el[s1 * 4 + g];
    float q2 = el[s2 * 4 + g], q3 = el[s3 * 4 + g];
    u16x8 f0 = *(const u16x8*)(fbase + (size_t)s0 * fstride);
    u16x8 f1 = *(const u16x8*)(fbase + (size_t)s1 * fstride);
    u16x8 f2 = *(const u16x8*)(fbase + (size_t)s2 * fstride);
    u16x8 f3 = *(const u16x8*)(fbase + (size_t)s3 * fstride);
    float e0 = q0 + er_g; e0 = (e0 >= 0.f) ? e0 : 0.2f * e0;
    float e1 = q1 + er_g; e1 = (e1 >= 0.f) ? e1 : 0.2f * e1;
    float e2 = q2 + er_g; e2 = (e2 >= 0.f) ? e2 : 0.2f * e2;
    float e3 = q3 + er_g; e3 = (e3 >= 0.f) ? e3 : 0.2f * e3;
    float p0 = __expf(e0), p1 = __expf(e1);
    float p2 = __expf(e2), p3 = __expf(e3);
    asum += (p0 + p1) + (p2 + p3);
#pragma unroll
    for (int k = 0; k < 8; ++k)
      acc[k] += p0 * bf2f(f0[k]) + p1 * bf2f(f1[k]) + p2 * bf2f(f2[k]) + p3 * bf2f(f3[k]);
  }
  for (; j < je; ++j) {
    int s = csr_src[j];
    float ev = el[s * 4 + g] + er_g;
    ev = (ev >= 0.f) ? ev : 0.2f * ev;
    float p = __expf(ev);
    asum += p;
    u16x8 fv = *(const u16x8*)(fbase + (size_t)s * fstride);
#pragma unroll
    for (int k = 0; k < 8; ++k) acc[k] += p * bf2f(fv[k]);
  }
  // ---- combine wave pair via LDS ----
  if (sub) {
#pragma unroll
    for (int k = 0; k < 8; ++k) lacc[nib][k * 64 + l] = acc[k];
    if ((l & 15) == 0) lsum[nib][g] = asum;
  }
  __syncthreads();
  if (sub) return;
#pragma unroll
  for (int k = 0; k < 8; ++k) acc[k] += lacc[nib][k * 64 + l];
  asum += lsum[nib][g];
  float inv = (cnt > 0) ? 1.f / asum : 1.f;
  u16x8 hv = *(const u16x8*)(hres + (size_t)wid * fstride + l * 8);
  float o[8];
#pragma unroll
  for (int k = 0; k < 8; ++k) o[k] = acc[k] * inv + bf2f(hv[k]);
  if constexpr (!FINAL) {
    u16x8 ob;
#pragma unroll
    for (int k = 0; k < 8; ++k) ob[k] = f2bf(fmaxf(o[k], 0.f));
    *(u16x8*)(hnext + (size_t)wid * 512 + l * 8) = ob;
  } else {
#pragma unroll
    for (int k = 0; k < 8; ++k) {
      float v = o[k];
      v += __shfl_xor(v, 16);
      v += __shfl_xor(v, 32);
      o[k] = v * 0.25f;
    }
    if (g == 0) {
      f32x4 o0 = (f32x4){o[0], o[1], o[2], o[3]};
      f32x4 o1 = (f32x4){o[4], o[5], o[6], o[7]};
      *(f32x4*)(h3 + (size_t)wid * 128 + l * 8) = o0;
      *(f32x4*)(h3 + (size_t)wid * 128 + l * 8 + 4) = o1;
      u16x8 hb;
#pragma unroll
      for (int k = 0; k < 8; ++k) hb[k] = f2bf(o[k]);
      *(u16x8*)(h3b + (size_t)wid * 128 + l * 8) = hb;
    }
  }
}

// ---- fused pair MLP v4: direct-to-register X gather + W in LDS (pre-swizzled) ----
template <int MODE>
__global__ __launch_bounds__(256) void k_pair_mlp(
    const unsigned short* __restrict__ X, const int* __restrict__ ia,
    const int* __restrict__ ib, const unsigned short* __restrict__ WbSwz,
    const float* __restrict__ b1, const float* __restrict__ W2,
    const float* __restrict__ b2, float* __restrict__ out, int npairs) {
  __shared__ __align__(16) unsigned short Ws[128 * 128];  // 32 KB
  const int t = threadIdx.x;
  const int l = t & 63, w = t >> 6;
#pragma unroll
  for (int i = 0; i < 8; ++i)
    gload_lds16(WbSwz + i * 2048 + w * 512 + l * 8, &Ws[i * 2048 + w * 512]);
  const int base = blockIdx.x * 128 + w * 32;
  bf16x8 af[2][4];
#pragma unroll
  for (int m = 0; m < 2; ++m) {
    int e = base + m * 16 + (l & 15);
    if (MODE == 1 && e >= npairs) e = npairs - 1;
    int sa, sb;
    if (MODE == 0) { sa = ia[e]; sb = ib[e]; }
    else           { sa = ia[e]; sb = e / KNN_K; }
    const unsigned short* pa = X + (size_t)sa * 128 + (l >> 4) * 8;
    const unsigned short* pb = X + (size_t)sb * 128 + (l >> 4) * 8;
#pragma unroll
    for (int kk = 0; kk < 4; ++kk) {
      u16x8 av = *(const u16x8*)(pa + kk * 32);
      u16x8 bv = *(const u16x8*)(pb + kk * 32);
      u16x8 xv;
#pragma unroll
      for (int j = 0; j < 8; ++j) xv[j] = f2bf(fabsf(bf2f(av[j]) - bf2f(bv[j])));
      af[m][kk] = *(bf16x8*)&xv;
    }
  }
  __syncthreads();  // W staged (drains vmcnt)
  float part[2][4];
#pragma unroll
  for (int m = 0; m < 2; ++m)
#pragma unroll
    for (int r = 0; r < 4; ++r) part[m][r] = 0.f;
#pragma unroll
  for (int n = 0; n < 8; ++n) {
    int rowv = n * 16 + (l & 15);
    bf16x8 bfr[4];
#pragma unroll
    for (int kk = 0; kk < 4; ++kk) {
      int sg = (kk * 4 + (l >> 4)) ^ (rowv & 15);
      bfr[kk] = *(const bf16x8*)&Ws[rowv * 128 + sg * 8];
    }
    f32x4 acc0 = (f32x4){0.f, 0.f, 0.f, 0.f};
    f32x4 acc1 = (f32x4){0.f, 0.f, 0.f, 0.f};
#pragma unroll
    for (int kk = 0; kk < 4; ++kk) {
      acc0 = __builtin_amdgcn_mfma_f32_16x16x32_bf16(af[0][kk], bfr[kk], acc0, 0, 0, 0);
      acc1 = __builtin_amdgcn_mfma_f32_16x16x32_bf16(af[1][kk], bfr[kk], acc1, 0, 0, 0);
    }
    float bb = b1[rowv], w2v = W2[rowv];
#pragma unroll
    for (int r = 0; r < 4; ++r) {
      part[0][r] += fmaxf(acc0[r] + bb, 0.f) * w2v;
      part[1][r] += fmaxf(acc1[r] + bb, 0.f) * w2v;
    }
  }
#pragma unroll
  for (int d = 1; d < 16; d <<= 1)
#pragma unroll
    for (int m = 0; m < 2; ++m)
#pragma unroll
      for (int r = 0; r < 4; ++r) part[m][r] += __shfl_xor(part[m][r], d);
  if ((l & 15) == 0) {
    int q = l >> 4;
    float b2v = b2[0];
#pragma unroll
    for (int m = 0; m < 2; ++m) {
      int e = base + m * 16 + q * 4;
      f32x4 ov;
#pragma unroll
      for (int r = 0; r < 4; ++r) ov[r] = sigmoidf(part[m][r] + b2v);
      if (e + 3 < npairs) *(f32x4*)(out + e) = ov;
      else {
#pragma unroll
        for (int r = 0; r < 4; ++r) if (e + r < npairs) out[e + r] = ov[r];
      }
    }
  }
}

// ---------------- entity segment sums ----------------
__global__ void k_ent_scatter(const float* __restrict__ h3, const float* __restrict__ pos,
                              const int* __restrict__ entity, float* __restrict__ ent_sum,
                              float* __restrict__ pos_sum, float* __restrict__ cnt) {
  int i = blockIdx.x * blockDim.x + threadIdx.x;
  if (i >= N_NODES * 32) return;
  int n = i >> 5, c = i & 31;
  int e = entity[n];
  f32x4 v = *(const f32x4*)(h3 + (size_t)n * 128 + c * 4);
  atomicAdd(&ent_sum[e * 128 + c * 4 + 0], v[0]);
  atomicAdd(&ent_sum[e * 128 + c * 4 + 1], v[1]);
  atomicAdd(&ent_sum[e * 128 + c * 4 + 2], v[2]);
  atomicAdd(&ent_sum[e * 128 + c * 4 + 3], v[3]);
  if (c == 0) {
    atomicAdd(&pos_sum[e * 2 + 0], pos[n * 2 + 0]);
    atomicAdd(&pos_sum[e * 2 + 1], pos[n * 2 + 1]);
    atomicAdd(&cnt[e], 1.f);
  }
}

// ---- fused entity: es = ent_sum@We^T+be ; esb = bf16(es) ; class = sigmoid(es@Wc^T+bc)
__global__ __launch_bounds__(128) void k_entity_fused(
    const float* __restrict__ ent_sum, const float* __restrict__ We,
    const float* __restrict__ be, const float* __restrict__ Wc,
    const float* __restrict__ bc, float* __restrict__ es,
    unsigned short* __restrict__ esb, float* __restrict__ out_class) {
  __shared__ float xs[128];
  __shared__ float ess[128];
  int e = blockIdx.x, t = threadIdx.x;
  xs[t] = ent_sum[(size_t)e * 128 + t];
  __syncthreads();
  const float* wrow = We + (size_t)t * 128;
  float s = be[t];
  for (int k = 0; k < 128; k += 4) {
    f32x4 wv = *(const f32x4*)(wrow + k);
    s += xs[k] * wv[0] + xs[k + 1] * wv[1] + xs[k + 2] * wv[2] + xs[k + 3] * wv[3];
  }
  es[(size_t)e * 128 + t] = s;
  esb[(size_t)e * 128 + t] = f2bf(s);
  ess[t] = s;
  __syncthreads();
  if (t < 4) {
    const float* crow = Wc + (size_t)t * 128;
    float c = bc[t];
    for (int k = 0; k < 128; ++k) c += ess[k] * crow[k];
    out_class[e * 4 + t] = sigmoidf(c);
  }
}

__global__ void k_entity_pos(const float* __restrict__ pos_sum, const float* __restrict__ cnt,
                             float* __restrict__ outpos, float* __restrict__ wspos) {
  int e = blockIdx.x * blockDim.x + threadIdx.x;
  if (e >= NENT) return;
  float c = fmaxf(cnt[e], 1.f);
  float x = pos_sum[e * 2] / c, y = pos_sum[e * 2 + 1] / c;
  outpos[e * 2] = x; outpos[e * 2 + 1] = y;
  wspos[e * 2] = x; wspos[e * 2 + 1] = y;
}

// ---------------- exact knn (K smallest d2, ties -> smaller index) ----------------
__global__ __launch_bounds__(256) void k_knn(const float* __restrict__ entpos,
                                             int* __restrict__ knn) {
  __shared__ float d2row[NENT];
  __shared__ float rv[256];
  __shared__ int ri[256];
  int i = blockIdx.x, t = threadIdx.x;
  float px = entpos[i * 2], py = entpos[i * 2 + 1];
  for (int j = t; j < NENT; j += 256) {
    float dx = px - entpos[j * 2], dy = py - entpos[j * 2 + 1];
    d2row[j] = __fadd_rn(__fmul_rn(dx, dx), __fmul_rn(dy, dy));
  }
  __syncthreads();
  for (int k = 0; k < KNN_K; ++k) {
    float bv = __builtin_inff(); int bi = 0x7fffffff;
    for (int j = t; j < NENT; j += 256) {
      float v = d2row[j];
      if (v < bv) { bv = v; bi = j; }
    }
    rv[t] = bv; ri[t] = bi;
    __syncthreads();
    for (int s = 128; s > 0; s >>= 1) {
      if (t < s) {
        if (rv[t + s] < rv[t] || (rv[t + s] == rv[t] && ri[t + s] < ri[t])) {
          rv[t] = rv[t + s]; ri[t] = ri[t + s];
        }
      }
      __syncthreads();
    }
    if (t == 0) { knn[i * KNN_K + k] = ri[0]; d2row[ri[0]] = __builtin_inff(); }
    __syncthreads();
  }
}

// =======================================================================
extern "C" void kernel_launch(void* const* d_in, const int* in_sizes, int n_in,
                              void* d_out, int out_size, void* d_ws, size_t ws_size,
                              hipStream_t stream) {
  const float* position = (const float*)d_in[0];
  const float* w_embed  = (const float*)d_in[1];
  const int*   src      = (const int*)d_in[2];
  const int*   dst      = (const int*)d_in[3];
  const int*   entity   = (const int*)d_in[4];
  const float* W1 = (const float*)d_in[5];
  const float* al1 = (const float*)d_in[6];
  const float* ar1 = (const float*)d_in[7];
  const float* Wr1 = (const float*)d_in[8];
  const float* W2 = (const float*)d_in[9];
  const float* al2 = (const float*)d_in[10];
  const float* ar2 = (const float*)d_in[11];
  const float* Wr2 = (const float*)d_in[12];
  const float* W3 = (const float*)d_in[13];
  const float* al3 = (const float*)d_in[14];
  const float* ar3 = (const float*)d_in[15];
  const float* Wr3 = (const float*)d_in[16];
  const float* Wg1 = (const float*)d_in[17];
  const float* bg1 = (const float*)d_in[18];
  const float* Wg2 = (const float*)d_in[19];
  const float* bg2 = (const float*)d_in[20];
  const float* We  = (const float*)d_in[21];
  const float* be  = (const float*)d_in[22];
  const float* Wl1 = (const float*)d_in[23];
  const float* bl1 = (const float*)d_in[24];
  const float* Wl2 = (const float*)d_in[25];
  const float* bl2 = (const float*)d_in[26];
  const float* Wc  = (const float*)d_in[27];
  const float* bc  = (const float*)d_in[28];

  float* out_groups = (float*)d_out;
  float* out_class  = out_groups + N_EDGES;
  float* out_pos    = out_class + NENT * 4;
  float* out_link   = out_pos + NENT * 2;

  char* ws = (char*)d_ws;
  size_t off = 0;
  auto carve = [&](size_t bytes) -> char* {
    char* p = ws + off;
    off = (off + bytes + 255) & ~(size_t)255;
    return p;
  };
  // fused GEMM output: [N, 1024] bf16 — cols 0..511 = feat, 512..1023 = hres
  unsigned short* featC = (unsigned short*)carve((size_t)N_NODES * 1024 * 2);
  unsigned short* hA = (unsigned short*)carve((size_t)N_NODES * 512 * 2);
  unsigned short* hB = (unsigned short*)carve((size_t)N_NODES * 512 * 2);
  unsigned short* wbf1 = (unsigned short*)carve((size_t)1024 * 128 * 2);  // [W1;Wr1]
  unsigned short* wbf2 = (unsigned short*)carve((size_t)1024 * 512 * 2);  // [W2;Wr2]
  unsigned short* wbf3 = (unsigned short*)carve((size_t)1024 * 512 * 2);  // [W3;Wr3]
  unsigned short* wg1b = (unsigned short*)carve(128 * 128 * 2);
  unsigned short* wl1b = (unsigned short*)carve(128 * 128 * 2);
  float* el = (float*)carve((size_t)N_NODES * 4 * 4);
  float* er = (float*)carve((size_t)N_NODES * 4 * 4);
  int* indeg = (int*)carve((size_t)N_NODES * 4);
  int* indptr = (int*)carve((size_t)(N_NODES + 1) * 4);
  int* cursor = (int*)carve((size_t)N_NODES * 4);
  int* csr_src = (int*)carve((size_t)N_EDGES * 4);
  float* h3 = (float*)carve((size_t)N_NODES * 128 * 4);
  unsigned short* h3b = (unsigned short*)carve((size_t)N_NODES * 128 * 2);
  float* ent_sum = (float*)carve((size_t)NENT * 128 * 4);
  float* pos_sum = (float*)carve((size_t)NENT * 2 * 4);
  float* cnt = (float*)carve((size_t)NENT * 4);
  float* es = (float*)carve((size_t)NENT * 128 * 4);
  unsigned short* esb = (unsigned short*)carve((size_t)NENT * 128 * 2);
  float* wspos = (float*)carve((size_t)NENT * 2 * 4);
  int* knn = (int*)carve((size_t)NENT * KNN_K * 4);

  // ---- CSR over dst (shared by all 3 GAT layers) ----
  hipMemsetAsync(indeg, 0, (size_t)N_NODES * 4, stream);
  k_hist<<<(N_EDGES + 255) / 256, 256, 0, stream>>>(dst, indeg);
  k_scan_fast<<<1, 1024, 0, stream>>>(indeg, indptr, cursor);
  k_scatter<<<(N_EDGES + 255) / 256, 256, 0, stream>>>(src, dst, cursor, csr_src);

  // ---- h0 + all weight conversions in one launch ----
  k_init<<<(943104 + 255) / 256, 256, 0, stream>>>(position, w_embed, W1, Wr1, W2, Wr2,
                                                   W3, Wr3, Wg1, Wl1, hA, wbf1, wbf2, wbf3,
                                                   wg1b, wl1b);

  // XCD-grouped 1D grid: 160 bm-slots (157 used) x 8 bn
  const int NBM = (N_NODES + 127) / 128;  // 157
  const int GGRID = 160 * 8;

  // ---- layer 1 (K=128), fused W|Wr GEMM ----
  k_gemm_bt<<<GGRID, 256, 0, stream>>>(hA, wbf1, featC, N_NODES, 1024, 128, NBM);
  k_el_er<<<5000, 256, 0, stream>>>(featC, 1024, al1, ar1, el, er);
  k_gat_agg<false><<<N_NODES / 2, 256, 0, stream>>>(featC, featC + 512, 1024, el, er, indptr,
                                                    csr_src, hB, nullptr, nullptr);

  // ---- layer 2 (K=512) ----
  k_gemm_bt<<<GGRID, 256, 0, stream>>>(hB, wbf2, featC, N_NODES, 1024, 512, NBM);
  k_el_er<<<5000, 256, 0, stream>>>(featC, 1024, al2, ar2, el, er);
  k_gat_agg<false><<<N_NODES / 2, 256, 0, stream>>>(featC, featC + 512, 1024, el, er, indptr,
                                                    csr_src, hA, nullptr, nullptr);

  // ---- layer 3 (K=512, no relu, head-mean) ----
  k_gemm_bt<<<GGRID, 256, 0, stream>>>(hA, wbf3, featC, N_NODES, 1024, 512, NBM);
  k_el_er<<<5000, 256, 0, stream>>>(featC, 1024, al3, ar3, el, er);
  k_gat_agg<true><<<N_NODES / 2, 256, 0, stream>>>(featC, featC + 512, 1024, el, er, indptr,
                                                   csr_src, nullptr, h3, h3b);

  // ---- groups_score (pair MLP v4 on bf16 h3) ----
  k_pair_mlp<0><<<N_EDGES / 128, 256, 0, stream>>>(h3b, src, dst, wg1b, bg1, Wg2, bg2,
                                                   out_groups, N_EDGES);

  // ---- entity path (ent_sum/pos_sum/cnt contiguous -> one memset) ----
  size_t zbytes = (size_t)((char*)cnt - (char*)ent_sum) + NENT * 4;
  hipMemsetAsync(ent_sum, 0, zbytes, stream);
  k_ent_scatter<<<(N_NODES * 32 + 255) / 256, 256, 0, stream>>>(h3, position, entity, ent_sum,
                                                                pos_sum, cnt);
  k_entity_fused<<<NENT, 128, 0, stream>>>(ent_sum, We, be, Wc, bc, es, esb, out_class);
  k_entity_pos<<<(NENT + 255) / 256, 256, 0, stream>>>(pos_sum, cnt, out_pos, wspos);
  k_knn<<<NENT, 256, 0, stream>>>(wspos, knn);
  k_pair_mlp<1><<<(NENT * KNN_K + 127) / 128, 256, 0, stream>>>(esb, knn, nullptr, wl1b, bl1,
                                                                Wl2, bl2, out_link,
                                                                NENT * KNN_K);
}

// Round 14
// 423.755 us; speedup vs baseline: 1.1662x; 1.0038x over previous
//
#include <hip/hip_runtime.h>
#include <math.h>

#define N_NODES 20000
#define N_EDGES 320000
#define NENT    2000
#define KNN_K   10

typedef __attribute__((ext_vector_type(4))) float f32x4;
typedef __attribute__((ext_vector_type(8))) short bf16x8;
typedef __attribute__((ext_vector_type(8))) unsigned short u16x8;
typedef __attribute__((ext_vector_type(4))) unsigned short u16x4;

__device__ __forceinline__ unsigned short f2bf(float f) {
  union { float f; unsigned u; } v; v.f = f;
  unsigned r = v.u + 0x7fffu + ((v.u >> 16) & 1u);
  return (unsigned short)(r >> 16);
}
__device__ __forceinline__ float bf2f(unsigned short u) {
  union { unsigned u; float f; } v; v.u = ((unsigned)u) << 16;
  return v.f;
}
__device__ __forceinline__ float sigmoidf(float x) {
  return 1.f / (1.f + __expf(-x));
}
// async global->LDS, 16B per lane; lds dest = wave-uniform base + lane*16
__device__ __forceinline__ void gload_lds16(const unsigned short* g, unsigned short* lds) {
  __builtin_amdgcn_global_load_lds(
      (const __attribute__((address_space(1))) unsigned int*)g,
      (__attribute__((address_space(3))) unsigned int*)lds, 16, 0, 0);
}

// ---- h0 build + ALL weight conversions + dst histogram in ONE launch ----
__global__ void k_init(
    const float* __restrict__ pos, const float* __restrict__ wemb,
    const float* __restrict__ W1, const float* __restrict__ Wr1,
    const float* __restrict__ W2, const float* __restrict__ Wr2,
    const float* __restrict__ W3, const float* __restrict__ Wr3,
    const float* __restrict__ Wg1, const float* __restrict__ Wl1,
    const int* __restrict__ dst, int* __restrict__ indeg,
    unsigned short* __restrict__ h0,
    unsigned short* __restrict__ wbf1, unsigned short* __restrict__ wbf2,
    unsigned short* __restrict__ wbf3, unsigned short* __restrict__ wg1b,
    unsigned short* __restrict__ wl1b) {
  int tid = blockIdx.x * blockDim.x + threadIdx.x;
  if (tid < 640000) {  // h0: N_NODES*128 elements, 4 per thread
    int i = tid * 4;
    int n = i >> 7, c = i & 127;
    u16x4 o;
    if (c == 0) {
      o[0] = f2bf(pos[n * 2]); o[1] = f2bf(pos[n * 2 + 1]);
      o[2] = f2bf(wemb[n * 126]); o[3] = f2bf(wemb[n * 126 + 1]);
    } else {
      const float* p = wemb + (size_t)n * 126 + (c - 2);
      o[0] = f2bf(p[0]); o[1] = f2bf(p[1]); o[2] = f2bf(p[2]); o[3] = f2bf(p[3]);
    }
    *(u16x4*)(h0 + i) = o;
    return;
  }
  if (tid >= 943104) {  // histogram over dst
    int e = tid - 943104;
    if (e < N_EDGES) atomicAdd(&indeg[dst[e]], 1);
    return;
  }
  int i4 = (tid - 640000) * 4;
  const float* src;
  unsigned short* dstp;
  if (i4 < 131072) {
    src = (i4 < 65536) ? (W1 + i4) : (Wr1 + i4 - 65536);
    dstp = wbf1 + i4;
  } else if ((i4 -= 131072) < 524288) {
    src = (i4 < 262144) ? (W2 + i4) : (Wr2 + i4 - 262144);
    dstp = wbf2 + i4;
  } else if ((i4 -= 524288) < 524288) {
    src = (i4 < 262144) ? (W3 + i4) : (Wr3 + i4 - 262144);
    dstp = wbf3 + i4;
  } else {
    i4 -= 524288;
    // swizzled 128x128: 4 consecutive k stay contiguous after swizzle
    const float* W = (i4 < 16384) ? Wg1 : Wl1;
    unsigned short* O = (i4 < 16384) ? wg1b : wl1b;
    int ii = i4 & 16383;
    int row = ii >> 7, k = ii & 127;
    int sg = (k >> 3) ^ (row & 15);
    src = W + ii;
    dstp = O + row * 128 + sg * 8 + (k & 7);
  }
  f32x4 v = *(const f32x4*)src;
  u16x4 o;
  o[0] = f2bf(v[0]); o[1] = f2bf(v[1]); o[2] = f2bf(v[2]); o[3] = f2bf(v[3]);
  *(u16x4*)dstp = o;
}

// ------- bf16 MFMA GEMM: C[M,Nc] = A[M,K] * B[Nc,K]^T, bf16 out, stride Nc -------
// 1D grid, XCD-grouped decomposition: the 8 bn-blocks of one bm share id%8
// (one XCD) so the A-panel is fetched once per XCD instead of 8x.
__global__ __launch_bounds__(256) void k_gemm_bt(
    const unsigned short* __restrict__ A, const unsigned short* __restrict__ B,
    unsigned short* __restrict__ C, int M, int Nc, int K, int nbm) {
  const int id = blockIdx.x;
  const int bm128 = (id & 7) + 8 * (id >> 6);
  const int bn128 = (id >> 3) & 7;
  if (bm128 >= nbm) return;  // uniform exit before any barrier
  __shared__ __align__(16) unsigned short As[128 * 64];
  __shared__ __align__(16) unsigned short Bs[128 * 64];
  const int bm = bm128 * 128, bn = bn128 * 128;
  const int t = threadIdx.x;
  const int l = t & 63, w = t >> 6;
  const int wr = w >> 1, wc = w & 1;
  f32x4 acc[4][4];
#pragma unroll
  for (int m = 0; m < 4; ++m)
#pragma unroll
    for (int n = 0; n < 4; ++n) acc[m][n] = (f32x4){0.f, 0.f, 0.f, 0.f};

  for (int kb = 0; kb < K; kb += 64) {
    __syncthreads();
#pragma unroll
    for (int i = 0; i < 4; ++i) {
      int c = t + 256 * i;         // 1024 16B-chunks per tile
      int row = c >> 3, cc = c & 7;
      int scc = cc ^ (row & 7);    // pre-swizzled SOURCE granule (read side keeps same XOR)
      int ar = bm + row; if (ar > M - 1) ar = M - 1;
      gload_lds16(A + (size_t)ar * K + kb + scc * 8, &As[(size_t)(w * 64 + 256 * i) * 8]);
      gload_lds16(B + (size_t)(bn + row) * K + kb + scc * 8,
                  &Bs[(size_t)(w * 64 + 256 * i) * 8]);
    }
    __syncthreads();
#pragma unroll
    for (int kk = 0; kk < 2; ++kk) {
      bf16x8 af[4], bfr[4];
#pragma unroll
      for (int m = 0; m < 4; ++m) {
        int row = wr * 64 + m * 16 + (l & 15);
        int g = (kk * 4 + (l >> 4)) ^ (row & 7);
        af[m] = *(const bf16x8*)&As[row * 64 + g * 8];
      }
#pragma unroll
      for (int n = 0; n < 4; ++n) {
        int row = wc * 64 + n * 16 + (l & 15);
        int g = (kk * 4 + (l >> 4)) ^ (row & 7);
        bfr[n] = *(const bf16x8*)&Bs[row * 64 + g * 8];
      }
#pragma unroll
      for (int m = 0; m < 4; ++m)
#pragma unroll
        for (int n = 0; n < 4; ++n)
          acc[m][n] = __builtin_amdgcn_mfma_f32_16x16x32_bf16(af[m], bfr[n], acc[m][n], 0, 0, 0);
    }
  }
#pragma unroll
  for (int m = 0; m < 4; ++m) {
    int r0 = bm + wr * 64 + m * 16 + ((l >> 4) << 2);
#pragma unroll
    for (int n = 0; n < 4; ++n) {
      int c0 = bn + wc * 64 + n * 16 + (l & 15);
#pragma unroll
      for (int r = 0; r < 4; ++r) {
        int row = r0 + r;
        if (row < M) C[(size_t)row * Nc + c0] = f2bf(acc[m][n][r]);
      }
    }
  }
}

// ---------------- el/er: per (node, head) dot(feat, al/ar) ----------------
__global__ void k_el_er(const unsigned short* __restrict__ feat, int fstride,
                        const float* __restrict__ al, const float* __restrict__ ar,
                        float* __restrict__ el, float* __restrict__ er) {
  int wid = (blockIdx.x * blockDim.x + threadIdx.x) >> 6;
  if (wid >= N_NODES) return;
  int l = threadIdx.x & 63;
  int g = l >> 4, q = l & 15;
  u16x8 fv = *(const u16x8*)(feat + (size_t)wid * fstride + l * 8);
  const float* alp = al + g * 128 + q * 8;
  const float* arp = ar + g * 128 + q * 8;
  float sl = 0.f, sr = 0.f;
#pragma unroll
  for (int j = 0; j < 8; ++j) { float f = bf2f(fv[j]); sl += f * alp[j]; sr += f * arp[j]; }
#pragma unroll
  for (int d = 1; d < 16; d <<= 1) { sl += __shfl_xor(sl, d); sr += __shfl_xor(sr, d); }
  if (q == 0) { el[wid * 4 + g] = sl; er[wid * 4 + g] = sr; }
}

// ---------------- CSR build ----------------
__global__ __launch_bounds__(1024) void k_scan_fast(const int* __restrict__ indeg,
                                                    int* __restrict__ indptr,
                                                    int* __restrict__ cursor) {
  __shared__ int wsum[16];
  const int t = threadIdx.x;
  const int l = t & 63, w = t >> 6;
  const int CH = 20;  // 1024*20 >= 20000
  int base = t * CH;
  int vals[CH];
  int s = 0;
#pragma unroll
  for (int i = 0; i < CH; ++i) {
    int idx = base + i;
    int v = (idx < N_NODES) ? indeg[idx] : 0;
    vals[i] = v;
    s += v;
  }
  int ss = s;
#pragma unroll
  for (int d = 1; d < 64; d <<= 1) { int o = __shfl_up(ss, d); if (l >= d) ss += o; }
  if (l == 63) wsum[w] = ss;
  __syncthreads();
  if (t < 16) {
    int v = wsum[t];
#pragma unroll
    for (int d = 1; d < 16; d <<= 1) { int o = __shfl_up(v, d); if (t >= d) v += o; }
    wsum[t] = v;
  }
  __syncthreads();
  int run = ((w > 0) ? wsum[w - 1] : 0) + ss - s;
  if (t == 0) indptr[0] = 0;
#pragma unroll
  for (int i = 0; i < CH; ++i) {
    int idx = base + i;
    if (idx < N_NODES) {
      cursor[idx] = run;
      run += vals[i];
      indptr[idx + 1] = run;
    }
  }
}

__global__ void k_scatter(const int* __restrict__ src, const int* __restrict__ dst,
                          int* __restrict__ cursor, int* __restrict__ csr_src) {
  int e = blockIdx.x * blockDim.x + threadIdx.x;
  if (e < N_EDGES) {
    int p = atomicAdd(&cursor[dst[e]], 1);
    csr_src[p] = src[e];
  }
}

// ---------------- GAT edge-softmax + aggregation ----------------
// 2 waves per node (edge-split halves), LDS combine; no-max softmax;
// 4-deep unrolled gather loop per wave. Grid = N_NODES/2 blocks x 256.
template <bool FINAL>
__global__ __launch_bounds__(256) void k_gat_agg(
    const unsigned short* __restrict__ feat, const unsigned short* __restrict__ hres,
    int fstride, const float* __restrict__ el, const float* __restrict__ er,
    const int* __restrict__ indptr, const int* __restrict__ csr_src,
    unsigned short* __restrict__ hnext, float* __restrict__ h3,
    unsigned short* __restrict__ h3b) {
  __shared__ float lacc[2][512];
  __shared__ float lsum[2][4];
  const int t = threadIdx.x;
  const int l = t & 63, w = t >> 6;
  const int nib = w >> 1, sub = w & 1;
  const int wid = blockIdx.x * 2 + nib;   // grid sized exactly: always < N_NODES
  const int g = l >> 4;
  int beg = indptr[wid], end = indptr[wid + 1];
  int cnt = end - beg;
  int half = (cnt + 1) >> 1;
  int jb = beg + sub * half;
  int je = sub ? end : (beg + half);
  float er_g = er[wid * 4 + g];
  float asum = 0.f;
  float acc[8];
#pragma unroll
  for (int k = 0; k < 8; ++k) acc[k] = 0.f;
  const unsigned short* fbase = feat + l * 8;
  int j = jb;
  for (; j + 4 <= je; j += 4) {
    int s0 = csr_src[j + 0], s1 = csr_src[j + 1];
    int s2 = csr_src[j + 2], s3 = csr_src[j + 3];
    float q0 = el[s0 * 4 + g], q1 = el[s1 * 4 + g];
    float q2 = el[s2 * 4 + g], q3 = el[s3 * 4 + g];
    u16x8 f0 = *(const u16x8*)(fbase + (size_t)s0 * fstride);
    u16x8 f1 = *(const u16x8*)(fbase + (size_t)s1 * fstride);
    u16x8 f2 = *(const u16x8*)(fbase + (size_t)s2 * fstride);
    u16x8 f3 = *(const u16x8*)(fbase + (size_t)s3 * fstride);
    float e0 = q0 + er_g; e0 = (e0 >= 0.f) ? e0 : 0.2f * e0;
    float e1 = q1 + er_g; e1 = (e1 >= 0.f) ? e1 : 0.2f * e1;
    float e2 = q2 + er_g; e2 = (e2 >= 0.f) ? e2 : 0.2f * e2;
    float e3 = q3 + er_g; e3 = (e3 >= 0.f) ? e3 : 0.2f * e3;
    float p0 = __expf(e0), p1 = __expf(e1);
    float p2 = __expf(e2), p3 = __expf(e3);
    asum += (p0 + p1) + (p2 + p3);
#pragma unroll
    for (int k = 0; k < 8; ++k)
      acc[k] += p0 * bf2f(f0[k]) + p1 * bf2f(f1[k]) + p2 * bf2f(f2[k]) + p3 * bf2f(f3[k]);
  }
  for (; j < je; ++j) {
    int s = csr_src[j];
    float ev = el[s * 4 + g] + er_g;
    ev = (ev >= 0.f) ? ev : 0.2f * ev;
    float p = __expf(ev);
    asum += p;
    u16x8 fv = *(const u16x8*)(fbase + (size_t)s * fstride);
#pragma unroll
    for (int k = 0; k < 8; ++k) acc[k] += p * bf2f(fv[k]);
  }
  // ---- combine wave pair via LDS ----
  if (sub) {
#pragma unroll
    for (int k = 0; k < 8; ++k) lacc[nib][k * 64 + l] = acc[k];
    if ((l & 15) == 0) lsum[nib][g] = asum;
  }
  __syncthreads();
  if (sub) return;
#pragma unroll
  for (int k = 0; k < 8; ++k) acc[k] += lacc[nib][k * 64 + l];
  asum += lsum[nib][g];
  float inv = (cnt > 0) ? 1.f / asum : 1.f;
  u16x8 hv = *(const u16x8*)(hres + (size_t)wid * fstride + l * 8);
  float o[8];
#pragma unroll
  for (int k = 0; k < 8; ++k) o[k] = acc[k] * inv + bf2f(hv[k]);
  if constexpr (!FINAL) {
    u16x8 ob;
#pragma unroll
    for (int k = 0; k < 8; ++k) ob[k] = f2bf(fmaxf(o[k], 0.f));
    *(u16x8*)(hnext + (size_t)wid * 512 + l * 8) = ob;
  } else {
#pragma unroll
    for (int k = 0; k < 8; ++k) {
      float v = o[k];
      v += __shfl_xor(v, 16);
      v += __shfl_xor(v, 32);
      o[k] = v * 0.25f;
    }
    if (g == 0) {
      f32x4 o0 = (f32x4){o[0], o[1], o[2], o[3]};
      f32x4 o1 = (f32x4){o[4], o[5], o[6], o[7]};
      *(f32x4*)(h3 + (size_t)wid * 128 + l * 8) = o0;
      *(f32x4*)(h3 + (size_t)wid * 128 + l * 8 + 4) = o1;
      u16x8 hb;
#pragma unroll
      for (int k = 0; k < 8; ++k) hb[k] = f2bf(o[k]);
      *(u16x8*)(h3b + (size_t)wid * 128 + l * 8) = hb;
    }
  }
}

// ---- fused pair MLP v4: direct-to-register X gather + W in LDS (pre-swizzled) ----
template <int MODE>
__global__ __launch_bounds__(256) void k_pair_mlp(
    const unsigned short* __restrict__ X, const int* __restrict__ ia,
    const int* __restrict__ ib, const unsigned short* __restrict__ WbSwz,
    const float* __restrict__ b1, const float* __restrict__ W2,
    const float* __restrict__ b2, float* __restrict__ out, int npairs) {
  __shared__ __align__(16) unsigned short Ws[128 * 128];  // 32 KB
  const int t = threadIdx.x;
  const int l = t & 63, w = t >> 6;
#pragma unroll
  for (int i = 0; i < 8; ++i)
    gload_lds16(WbSwz + i * 2048 + w * 512 + l * 8, &Ws[i * 2048 + w * 512]);
  const int base = blockIdx.x * 128 + w * 32;
  bf16x8 af[2][4];
#pragma unroll
  for (int m = 0; m < 2; ++m) {
    int e = base + m * 16 + (l & 15);
    if (MODE == 1 && e >= npairs) e = npairs - 1;
    int sa, sb;
    if (MODE == 0) { sa = ia[e]; sb = ib[e]; }
    else           { sa = ia[e]; sb = e / KNN_K; }
    const unsigned short* pa = X + (size_t)sa * 128 + (l >> 4) * 8;
    const unsigned short* pb = X + (size_t)sb * 128 + (l >> 4) * 8;
#pragma unroll
    for (int kk = 0; kk < 4; ++kk) {
      u16x8 av = *(const u16x8*)(pa + kk * 32);
      u16x8 bv = *(const u16x8*)(pb + kk * 32);
      u16x8 xv;
#pragma unroll
      for (int j = 0; j < 8; ++j) xv[j] = f2bf(fabsf(bf2f(av[j]) - bf2f(bv[j])));
      af[m][kk] = *(bf16x8*)&xv;
    }
  }
  __syncthreads();  // W staged (drains vmcnt)
  float part[2][4];
#pragma unroll
  for (int m = 0; m < 2; ++m)
#pragma unroll
    for (int r = 0; r < 4; ++r) part[m][r] = 0.f;
#pragma unroll
  for (int n = 0; n < 8; ++n) {
    int rowv = n * 16 + (l & 15);
    bf16x8 bfr[4];
#pragma unroll
    for (int kk = 0; kk < 4; ++kk) {
      int sg = (kk * 4 + (l >> 4)) ^ (rowv & 15);
      bfr[kk] = *(const bf16x8*)&Ws[rowv * 128 + sg * 8];
    }
    f32x4 acc0 = (f32x4){0.f, 0.f, 0.f, 0.f};
    f32x4 acc1 = (f32x4){0.f, 0.f, 0.f, 0.f};
#pragma unroll
    for (int kk = 0; kk < 4; ++kk) {
      acc0 = __builtin_amdgcn_mfma_f32_16x16x32_bf16(af[0][kk], bfr[kk], acc0, 0, 0, 0);
      acc1 = __builtin_amdgcn_mfma_f32_16x16x32_bf16(af[1][kk], bfr[kk], acc1, 0, 0, 0);
    }
    float bb = b1[rowv], w2v = W2[rowv];
#pragma unroll
    for (int r = 0; r < 4; ++r) {
      part[0][r] += fmaxf(acc0[r] + bb, 0.f) * w2v;
      part[1][r] += fmaxf(acc1[r] + bb, 0.f) * w2v;
    }
  }
#pragma unroll
  for (int d = 1; d < 16; d <<= 1)
#pragma unroll
    for (int m = 0; m < 2; ++m)
#pragma unroll
      for (int r = 0; r < 4; ++r) part[m][r] += __shfl_xor(part[m][r], d);
  if ((l & 15) == 0) {
    int q = l >> 4;
    float b2v = b2[0];
#pragma unroll
    for (int m = 0; m < 2; ++m) {
      int e = base + m * 16 + q * 4;
      f32x4 ov;
#pragma unroll
      for (int r = 0; r < 4; ++r) ov[r] = sigmoidf(part[m][r] + b2v);
      if (e + 3 < npairs) *(f32x4*)(out + e) = ov;
      else {
#pragma unroll
        for (int r = 0; r < 4; ++r) if (e + r < npairs) out[e + r] = ov[r];
      }
    }
  }
}

// ---------------- entity segment sums ----------------
__global__ void k_ent_scatter(const float* __restrict__ h3, const float* __restrict__ pos,
                              const int* __restrict__ entity, float* __restrict__ ent_sum,
                              float* __restrict__ pos_sum, float* __restrict__ cnt) {
  int i = blockIdx.x * blockDim.x + threadIdx.x;
  if (i >= N_NODES * 32) return;
  int n = i >> 5, c = i & 31;
  int e = entity[n];
  f32x4 v = *(const f32x4*)(h3 + (size_t)n * 128 + c * 4);
  atomicAdd(&ent_sum[e * 128 + c * 4 + 0], v[0]);
  atomicAdd(&ent_sum[e * 128 + c * 4 + 1], v[1]);
  atomicAdd(&ent_sum[e * 128 + c * 4 + 2], v[2]);
  atomicAdd(&ent_sum[e * 128 + c * 4 + 3], v[3]);
  if (c == 0) {
    atomicAdd(&pos_sum[e * 2 + 0], pos[n * 2 + 0]);
    atomicAdd(&pos_sum[e * 2 + 1], pos[n * 2 + 1]);
    atomicAdd(&cnt[e], 1.f);
  }
}

// ---- fused entity: es/esb/class + centroid positions ----
__global__ __launch_bounds__(128) void k_entity_fused(
    const float* __restrict__ ent_sum, const float* __restrict__ We,
    const float* __restrict__ be, const float* __restrict__ Wc,
    const float* __restrict__ bc, const float* __restrict__ pos_sum,
    const float* __restrict__ cnt, float* __restrict__ es,
    unsigned short* __restrict__ esb, float* __restrict__ out_class,
    float* __restrict__ outpos, float* __restrict__ wspos) {
  __shared__ float xs[128];
  __shared__ float ess[128];
  int e = blockIdx.x, t = threadIdx.x;
  xs[t] = ent_sum[(size_t)e * 128 + t];
  if (t < 2) {
    float c = fmaxf(cnt[e], 1.f);
    float v = pos_sum[e * 2 + t] / c;
    outpos[e * 2 + t] = v;
    wspos[e * 2 + t] = v;
  }
  __syncthreads();
  const float* wrow = We + (size_t)t * 128;
  float s = be[t];
  for (int k = 0; k < 128; k += 4) {
    f32x4 wv = *(const f32x4*)(wrow + k);
    s += xs[k] * wv[0] + xs[k + 1] * wv[1] + xs[k + 2] * wv[2] + xs[k + 3] * wv[3];
  }
  es[(size_t)e * 128 + t] = s;
  esb[(size_t)e * 128 + t] = f2bf(s);
  ess[t] = s;
  __syncthreads();
  if (t < 4) {
    const float* crow = Wc + (size_t)t * 128;
    float c = bc[t];
    for (int k = 0; k < 128; ++k) c += ess[k] * crow[k];
    out_class[e * 4 + t] = sigmoidf(c);
  }
}

// ---------------- exact knn v2 (wave-shfl reduce, 2 barriers per k) ----------------
__global__ __launch_bounds__(256) void k_knn(const float* __restrict__ entpos,
                                             int* __restrict__ knn) {
  __shared__ float d2row[NENT];
  __shared__ float rv4[4];
  __shared__ int ri4[4];
  int i = blockIdx.x, t = threadIdx.x;
  int l = t & 63, w = t >> 6;
  float px = entpos[i * 2], py = entpos[i * 2 + 1];
  for (int j = t; j < NENT; j += 256) {
    float dx = px - entpos[j * 2], dy = py - entpos[j * 2 + 1];
    d2row[j] = __fadd_rn(__fmul_rn(dx, dx), __fmul_rn(dy, dy));
  }
  __syncthreads();
  for (int k = 0; k < KNN_K; ++k) {
    float bv = __builtin_inff();
    int bi = 0x7fffffff;
    for (int j = t; j < NENT; j += 256) {
      float v = d2row[j];
      if (v < bv) { bv = v; bi = j; }   // j ascending -> first (smallest) wins ties
    }
#pragma unroll
    for (int d = 1; d < 64; d <<= 1) {
      float ov = __shfl_xor(bv, d);
      int oi = __shfl_xor(bi, d);
      if (ov < bv || (ov == bv && oi < bi)) { bv = ov; bi = oi; }
    }
    if (l == 0) { rv4[w] = bv; ri4[w] = bi; }
    __syncthreads();
    if (t == 0) {
      float fv = rv4[0]; int fi = ri4[0];
#pragma unroll
      for (int q = 1; q < 4; ++q) {
        if (rv4[q] < fv || (rv4[q] == fv && ri4[q] < fi)) { fv = rv4[q]; fi = ri4[q]; }
      }
      knn[i * KNN_K + k] = fi;
      d2row[fi] = __builtin_inff();
    }
    __syncthreads();
  }
}

// =======================================================================
extern "C" void kernel_launch(void* const* d_in, const int* in_sizes, int n_in,
                              void* d_out, int out_size, void* d_ws, size_t ws_size,
                              hipStream_t stream) {
  const float* position = (const float*)d_in[0];
  const float* w_embed  = (const float*)d_in[1];
  const int*   src      = (const int*)d_in[2];
  const int*   dst      = (const int*)d_in[3];
  const int*   entity   = (const int*)d_in[4];
  const float* W1 = (const float*)d_in[5];
  const float* al1 = (const float*)d_in[6];
  const float* ar1 = (const float*)d_in[7];
  const float* Wr1 = (const float*)d_in[8];
  const float* W2 = (const float*)d_in[9];
  const float* al2 = (const float*)d_in[10];
  const float* ar2 = (const float*)d_in[11];
  const float* Wr2 = (const float*)d_in[12];
  const float* W3 = (const float*)d_in[13];
  const float* al3 = (const float*)d_in[14];
  const float* ar3 = (const float*)d_in[15];
  const float* Wr3 = (const float*)d_in[16];
  const float* Wg1 = (const float*)d_in[17];
  const float* bg1 = (const float*)d_in[18];
  const float* Wg2 = (const float*)d_in[19];
  const float* bg2 = (const float*)d_in[20];
  const float* We  = (const float*)d_in[21];
  const float* be  = (const float*)d_in[22];
  const float* Wl1 = (const float*)d_in[23];
  const float* bl1 = (const float*)d_in[24];
  const float* Wl2 = (const float*)d_in[25];
  const float* bl2 = (const float*)d_in[26];
  const float* Wc  = (const float*)d_in[27];
  const float* bc  = (const float*)d_in[28];

  float* out_groups = (float*)d_out;
  float* out_class  = out_groups + N_EDGES;
  float* out_pos    = out_class + NENT * 4;
  float* out_link   = out_pos + NENT * 2;

  char* ws = (char*)d_ws;
  size_t off = 0;
  auto carve = [&](size_t bytes) -> char* {
    char* p = ws + off;
    off = (off + bytes + 255) & ~(size_t)255;
    return p;
  };
  // fused GEMM output: [N, 1024] bf16 — cols 0..511 = feat, 512..1023 = hres
  unsigned short* featC = (unsigned short*)carve((size_t)N_NODES * 1024 * 2);
  unsigned short* hA = (unsigned short*)carve((size_t)N_NODES * 512 * 2);
  unsigned short* hB = (unsigned short*)carve((size_t)N_NODES * 512 * 2);
  unsigned short* wbf1 = (unsigned short*)carve((size_t)1024 * 128 * 2);  // [W1;Wr1]
  unsigned short* wbf2 = (unsigned short*)carve((size_t)1024 * 512 * 2);  // [W2;Wr2]
  unsigned short* wbf3 = (unsigned short*)carve((size_t)1024 * 512 * 2);  // [W3;Wr3]
  unsigned short* wg1b = (unsigned short*)carve(128 * 128 * 2);
  unsigned short* wl1b = (unsigned short*)carve(128 * 128 * 2);
  float* el = (float*)carve((size_t)N_NODES * 4 * 4);
  float* er = (float*)carve((size_t)N_NODES * 4 * 4);
  int* indeg = (int*)carve((size_t)N_NODES * 4);
  int* indptr = (int*)carve((size_t)(N_NODES + 1) * 4);
  int* cursor = (int*)carve((size_t)N_NODES * 4);
  int* csr_src = (int*)carve((size_t)N_EDGES * 4);
  float* h3 = (float*)carve((size_t)N_NODES * 128 * 4);
  unsigned short* h3b = (unsigned short*)carve((size_t)N_NODES * 128 * 2);
  float* ent_sum = (float*)carve((size_t)NENT * 128 * 4);
  float* pos_sum = (float*)carve((size_t)NENT * 2 * 4);
  float* cnt = (float*)carve((size_t)NENT * 4);
  float* es = (float*)carve((size_t)NENT * 128 * 4);
  unsigned short* esb = (unsigned short*)carve((size_t)NENT * 128 * 2);
  float* wspos = (float*)carve((size_t)NENT * 2 * 4);
  int* knn = (int*)carve((size_t)NENT * KNN_K * 4);

  // ---- init (h0 + weights + dst histogram) ----
  hipMemsetAsync(indeg, 0, (size_t)N_NODES * 4, stream);
  k_init<<<(943104 + N_EDGES + 255) / 256, 256, 0, stream>>>(
      position, w_embed, W1, Wr1, W2, Wr2, W3, Wr3, Wg1, Wl1, dst, indeg,
      hA, wbf1, wbf2, wbf3, wg1b, wl1b);
  k_scan_fast<<<1, 1024, 0, stream>>>(indeg, indptr, cursor);
  k_scatter<<<(N_EDGES + 255) / 256, 256, 0, stream>>>(src, dst, cursor, csr_src);

  // XCD-grouped 1D grid: 160 bm-slots (157 used) x 8 bn
  const int NBM = (N_NODES + 127) / 128;  // 157
  const int GGRID = 160 * 8;

  // ---- layer 1 (K=128), fused W|Wr GEMM ----
  k_gemm_bt<<<GGRID, 256, 0, stream>>>(hA, wbf1, featC, N_NODES, 1024, 128, NBM);
  k_el_er<<<5000, 256, 0, stream>>>(featC, 1024, al1, ar1, el, er);
  k_gat_agg<false><<<N_NODES / 2, 256, 0, stream>>>(featC, featC + 512, 1024, el, er, indptr,
                                                    csr_src, hB, nullptr, nullptr);

  // ---- layer 2 (K=512) ----
  k_gemm_bt<<<GGRID, 256, 0, stream>>>(hB, wbf2, featC, N_NODES, 1024, 512, NBM);
  k_el_er<<<5000, 256, 0, stream>>>(featC, 1024, al2, ar2, el, er);
  k_gat_agg<false><<<N_NODES / 2, 256, 0, stream>>>(featC, featC + 512, 1024, el, er, indptr,
                                                    csr_src, hA, nullptr, nullptr);

  // ---- layer 3 (K=512, no relu, head-mean) ----
  k_gemm_bt<<<GGRID, 256, 0, stream>>>(hA, wbf3, featC, N_NODES, 1024, 512, NBM);
  k_el_er<<<5000, 256, 0, stream>>>(featC, 1024, al3, ar3, el, er);
  k_gat_agg<true><<<N_NODES / 2, 256, 0, stream>>>(featC, featC + 512, 1024, el, er, indptr,
                                                   csr_src, nullptr, h3, h3b);

  // ---- groups_score (pair MLP v4 on bf16 h3) ----
  k_pair_mlp<0><<<N_EDGES / 128, 256, 0, stream>>>(h3b, src, dst, wg1b, bg1, Wg2, bg2,
                                                   out_groups, N_EDGES);

  // ---- entity path (ent_sum/pos_sum/cnt contiguous -> one memset) ----
  size_t zbytes = (size_t)((char*)cnt - (char*)ent_sum) + NENT * 4;
  hipMemsetAsync(ent_sum, 0, zbytes, stream);
  k_ent_scatter<<<(N_NODES * 32 + 255) / 256, 256, 0, stream>>>(h3, position, entity, ent_sum,
                                                                pos_sum, cnt);
  k_entity_fused<<<NENT, 128, 0, stream>>>(ent_sum, We, be, Wc, bc, pos_sum, cnt,
                                           es, esb, out_class, out_pos, wspos);
  k_knn<<<NENT, 256, 0, stream>>>(wspos, knn);
  k_pair_mlp<1><<<(NENT * KNN_K + 127) / 128, 256, 0, stream>>>(esb, knn, nullptr, wl1b, bl1,
                                                                Wl2, bl2, out_link,
                                                                NENT * KNN_K);
}